// Round 15
// baseline (170.208 us; speedup 1.0000x reference)
//
#include <hip/hip_runtime.h>

#define NN 50000
#define DIM 64
#define NE 1250000
#define NPARTS 196  // ceil(50000/256)

// ---- counting-sort CSR build: 64 edge-slices x 8 row-ranges ----
#define NSL 64
#define SLICEB 19532          // ceil(NE / NSL)
#define RANGE 6250            // NN / 8 rows per range
#define CSTRIDE 50048         // padded row stride of cnt matrix

// bf16 helpers (RNE pack, cheap unpack)
__device__ __forceinline__ unsigned short f2b(float f) {
    unsigned int b = __builtin_bit_cast(unsigned int, f);
    b = (b + 0x7fffu + ((b >> 16) & 1u)) >> 16;
    return (unsigned short)b;
}
__device__ __forceinline__ float blo(unsigned int u) {
    return __builtin_bit_cast(float, u << 16);
}
__device__ __forceinline__ float bhi(unsigned int u) {
    return __builtin_bit_cast(float, u & 0xffff0000u);
}

// ---------------- fp32 -> bf16 pack of the embedding table ----------------
__global__ __launch_bounds__(256) void k_cvt(const float* __restrict__ in,
                                             unsigned short* __restrict__ out) {
    int t = blockIdx.x * blockDim.x + threadIdx.x;  // 8 elems per thread
    if (t >= NN * DIM / 8) return;
    const float4* p = (const float4*)in + t * 2;
    float4 a = p[0], b = p[1];
    ushort4 u0 = {f2b(a.x), f2b(a.y), f2b(a.z), f2b(a.w)};
    ushort4 u1 = {f2b(b.x), f2b(b.y), f2b(b.z), f2b(b.w)};
    ((ushort4*)out)[t * 2 + 0] = u0;
    ((ushort4*)out)[t * 2 + 1] = u1;
}

// ---------------- per-slice LDS histogram (NO global atomics) ----------------
// bid -> slice s = (bid&7)|((bid>>6)<<3), range rng = (bid>>3)&7.
// bid%8 == s%8 -> same-slice blocks on one XCD: slice read into L2 once.
__global__ __launch_bounds__(512) void k_hist(const int* __restrict__ row,
                                              unsigned short* __restrict__ cnt) {
    __shared__ int h[RANGE];
    int bid = blockIdx.x;
    int s   = (bid & 7) | ((bid >> 6) << 3);
    int rng = (bid >> 3) & 7;
    int lo = rng * RANGE;
    int tid = threadIdx.x;
    for (int i = tid; i < RANGE; i += 512) h[i] = 0;
    __syncthreads();
    int beg = s * SLICEB;
    int end = beg + SLICEB;
    if (end > NE) end = NE;
    for (int e = beg + tid; e < end; e += 512) {
        int r = row[e] - lo;
        if ((unsigned)r < RANGE) atomicAdd(&h[r], 1);  // LDS atomic
    }
    __syncthreads();
    unsigned short* c = cnt + s * CSTRIDE + lo;
    for (int i = tid; i < RANGE; i += 512) c[i] = (unsigned short)h[i];
}

// ---------------- per-row scan over slices: cnt -> rel offsets, deg ----------------
__global__ __launch_bounds__(256) void k_rowscan(unsigned short* __restrict__ cnt,
                                                 int* __restrict__ deg) {
    int r = blockIdx.x * blockDim.x + threadIdx.x;
    if (r >= NN) return;
    int acc = 0;
#pragma unroll
    for (int s = 0; s < NSL; ++s) {
        int c = cnt[s * CSTRIDE + r];
        cnt[s * CSTRIDE + r] = (unsigned short)acc;  // exclusive within-row offset
        acc += c;
    }
    deg[r] = acc;
}

// ---------------- hierarchical exclusive scan over deg -> offs ----------------
__global__ __launch_bounds__(256) void k_scan_part(const int* __restrict__ deg,
                                                   int* __restrict__ partial) {
    __shared__ int s[256];
    int t = threadIdx.x;
    int i = blockIdx.x * 256 + t;
    s[t] = (i < NN) ? deg[i] : 0;
    __syncthreads();
    for (int off = 128; off > 0; off >>= 1) {
        if (t < off) s[t] += s[t + off];
        __syncthreads();
    }
    if (t == 0) partial[blockIdx.x] = s[0];
}

__global__ __launch_bounds__(256) void k_scan_top(int* __restrict__ partial) {
    __shared__ int s[256];
    int t = threadIdx.x;
    int v = (t < NPARTS) ? partial[t] : 0;
    s[t] = v;
    __syncthreads();
    for (int off = 1; off < 256; off <<= 1) {
        int x = (t >= off) ? s[t - off] : 0;
        __syncthreads();
        s[t] += x;
        __syncthreads();
    }
    if (t < NPARTS) partial[t] = s[t] - v;
}

__global__ __launch_bounds__(256) void k_scan_final(const int* __restrict__ deg,
                                                    const int* __restrict__ partial,
                                                    int* __restrict__ offs) {
    __shared__ int s[256];
    int t = threadIdx.x;
    int i = blockIdx.x * 256 + t;
    int v = (i < NN) ? deg[i] : 0;
    s[t] = v;
    __syncthreads();
    for (int off = 1; off < 256; off <<= 1) {
        int x = (t >= off) ? s[t - off] : 0;
        __syncthreads();
        s[t] += x;
        __syncthreads();
    }
    int excl = s[t] - v;
    if (i <= NN) offs[i] = partial[blockIdx.x] + excl;  // offs[NN] = NE
}

// ---------------- CSR fill via LDS cursor (NO global atomics) ----------------
// bid -> s = bid>>3, rng = bid&7: all 64 blocks writing a range's csr region
// run on ONE XCD (round-robin), so its 625 KB of csr lines can accumulate
// dirty in that XCD's L2 and evict as full lines. Round-14 lesson: that alone
// is insufficient because the 10 MB/XCD edge-read STREAM evicts the dirty
// lines -> NON-TEMPORAL loads keep the stream out of L2 (reads have no reuse
// under this mapping; cross-XCD slice re-reads are L3-served).
__global__ __launch_bounds__(512) void k_fillb(const int* __restrict__ row,
                                               const int* __restrict__ col,
                                               const int* __restrict__ offs,
                                               const unsigned short* __restrict__ cnt,
                                               int* __restrict__ csr) {
    __shared__ int cur[RANGE];
    int bid = blockIdx.x;
    int s   = bid >> 3;
    int rng = bid & 7;
    int lo = rng * RANGE;
    int tid = threadIdx.x;
    const unsigned short* c = cnt + s * CSTRIDE + lo;
    const int* o = offs + lo;
    for (int i = tid; i < RANGE; i += 512) cur[i] = o[i] + c[i];
    __syncthreads();
    int beg = s * SLICEB;
    int end = beg + SLICEB;
    if (end > NE) end = NE;
    for (int e = beg + tid; e < end; e += 512) {
        int r = __builtin_nontemporal_load(&row[e]) - lo;  // nt: don't evict csr
        if ((unsigned)r < RANGE) {
            int pos = atomicAdd(&cur[r], 1);  // LDS atomic
            csr[pos] = __builtin_nontemporal_load(&col[e]);
        }
    }
}

// ---------------- one propagation layer (bf16 gather, fp32 accum) ----------------
// 4 nodes per wave: lane>>4 = node in wave, lane&15 = feature-quad (uint2 load).
template <int PHASE>
__global__ __launch_bounds__(256) void k_layer(const unsigned short* __restrict__ xin16,
                                               const float* __restrict__ emb,
                                               unsigned short* __restrict__ xout16,
                                               float* __restrict__ out,
                                               const int* __restrict__ offs,
                                               const int* __restrict__ csr) {
    int wid = (blockIdx.x * blockDim.x + threadIdx.x) >> 6;
    int lane = threadIdx.x & 63;
    int sub = lane >> 4;    // node within wave (0..3)
    int sl = lane & 15;     // feature-quad index (0..15)
    int n = 4 * wid + sub;
    if (n >= NN) return;
    int beg = offs[n];
    int end = offs[n + 1];
    const unsigned short* xq = xin16 + sl * 4;

    float a0 = 0.f, a1 = 0.f, a2 = 0.f, a3 = 0.f;
    float b0 = 0.f, b1 = 0.f, b2 = 0.f, b3 = 0.f;
    int e = beg;
    for (; e + 8 <= end; e += 8) {
        int c0 = csr[e + 0], c1 = csr[e + 1], c2 = csr[e + 2], c3 = csr[e + 3];
        int c4 = csr[e + 4], c5 = csr[e + 5], c6 = csr[e + 6], c7 = csr[e + 7];
        uint2 u0 = *(const uint2*)(xq + c0 * DIM);
        uint2 u1 = *(const uint2*)(xq + c1 * DIM);
        uint2 u2 = *(const uint2*)(xq + c2 * DIM);
        uint2 u3 = *(const uint2*)(xq + c3 * DIM);
        uint2 u4 = *(const uint2*)(xq + c4 * DIM);
        uint2 u5 = *(const uint2*)(xq + c5 * DIM);
        uint2 u6 = *(const uint2*)(xq + c6 * DIM);
        uint2 u7 = *(const uint2*)(xq + c7 * DIM);
        a0 += blo(u0.x) + blo(u4.x);  b0 += blo(u1.x) + blo(u5.x);
        a1 += bhi(u0.x) + bhi(u4.x);  b1 += bhi(u1.x) + bhi(u5.x);
        a2 += blo(u0.y) + blo(u4.y);  b2 += blo(u1.y) + blo(u5.y);
        a3 += bhi(u0.y) + bhi(u4.y);  b3 += bhi(u1.y) + bhi(u5.y);
        a0 += blo(u2.x) + blo(u6.x);  b0 += blo(u3.x) + blo(u7.x);
        a1 += bhi(u2.x) + bhi(u6.x);  b1 += bhi(u3.x) + bhi(u7.x);
        a2 += blo(u2.y) + blo(u6.y);  b2 += blo(u3.y) + blo(u7.y);
        a3 += bhi(u2.y) + bhi(u6.y);  b3 += bhi(u3.y) + bhi(u7.y);
    }
    for (; e < end; ++e) {
        uint2 u = *(const uint2*)(xq + csr[e] * DIM);
        a0 += blo(u.x);
        a1 += bhi(u.x);
        a2 += blo(u.y);
        a3 += bhi(u.y);
    }

    int d = end - beg;
    float inv = (d > 0) ? 1.0f / (float)d : 0.0f;
    float v0 = (a0 + b0) * inv;
    float v1 = (a1 + b1) * inv;
    float v2 = (a2 + b2) * inv;
    float v3 = (a3 + b3) * inv;

    int o = n * DIM + sl * 4;
    if (PHASE == 0) {
        float4 ev = *(const float4*)(emb + o);
        float4 ov = {0.25f * (ev.x + v0), 0.25f * (ev.y + v1),
                     0.25f * (ev.z + v2), 0.25f * (ev.w + v3)};
        *(float4*)(out + o) = ov;
        uint2 pk = {(unsigned int)f2b(v0) | ((unsigned int)f2b(v1) << 16),
                    (unsigned int)f2b(v2) | ((unsigned int)f2b(v3) << 16)};
        *(uint2*)(xout16 + o) = pk;
    } else if (PHASE == 1) {
        float4 cur = *(const float4*)(out + o);
        cur.x += 0.25f * v0;
        cur.y += 0.25f * v1;
        cur.z += 0.25f * v2;
        cur.w += 0.25f * v3;
        *(float4*)(out + o) = cur;
        uint2 pk = {(unsigned int)f2b(v0) | ((unsigned int)f2b(v1) << 16),
                    (unsigned int)f2b(v2) | ((unsigned int)f2b(v3) << 16)};
        *(uint2*)(xout16 + o) = pk;
    } else {
        float4 cur = *(const float4*)(out + o);
        cur.x += 0.25f * v0;
        cur.y += 0.25f * v1;
        cur.z += 0.25f * v2;
        cur.w += 0.25f * v3;
        *(float4*)(out + o) = cur;
    }
}

extern "C" void kernel_launch(void* const* d_in, const int* in_sizes, int n_in,
                              void* d_out, int out_size, void* d_ws, size_t ws_size,
                              hipStream_t stream) {
    const int* edge = (const int*)d_in[0];
    const int* row = edge;        // edge_index[0]
    const int* col = edge + NE;   // edge_index[1]
    const float* emb = (const float*)d_in[1];
    float* out = (float*)d_out;

    // workspace layout (~31 MB)
    int* deg    = (int*)d_ws;                                // 50048 ints
    int* offs   = deg + 50048;                               // 50112 ints
    int* partial= offs + 50112;                              // 256 ints
    int* csr    = partial + 256;                             // 1250048 ints
    unsigned short* cnt = (unsigned short*)(csr + 1250048);  // 64*50048 ushort (6.4MB)
    unsigned short* x0  = cnt + NSL * CSTRIDE;               // 3.2M ushort
    unsigned short* xa  = x0 + NN * DIM;
    unsigned short* xb  = xa + NN * DIM;

    k_cvt       <<<(NN * DIM / 8 + 255) / 256, 256, 0, stream>>>(emb, x0);
    k_hist      <<<NSL * 8, 512, 0, stream>>>(row, cnt);
    k_rowscan   <<<NPARTS, 256, 0, stream>>>(cnt, deg);
    k_scan_part <<<NPARTS, 256, 0, stream>>>(deg, partial);
    k_scan_top  <<<1, 256, 0, stream>>>(partial);
    k_scan_final<<<NPARTS, 256, 0, stream>>>(deg, partial, offs);
    k_fillb     <<<NSL * 8, 512, 0, stream>>>(row, col, offs, cnt, csr);

    // 4 nodes per wave: 12500 waves -> 3125 blocks of 256
    int layer_blocks = (NN / 4 * 64) / 256;  // 3125
    k_layer<0><<<layer_blocks, 256, 0, stream>>>(x0, emb, xa, out, offs, csr);
    k_layer<1><<<layer_blocks, 256, 0, stream>>>(xa, nullptr, xb, out, offs, csr);
    k_layer<2><<<layer_blocks, 256, 0, stream>>>(xb, nullptr, nullptr, out, offs, csr);
}

// Round 16
// 165.048 us; speedup vs baseline: 1.0313x; 1.0313x over previous
//
#include <hip/hip_runtime.h>

#define NN 50000
#define DIM 64
#define NE 1250000
#define NPARTS 196  // ceil(50000/256)

// ---- counting-sort CSR build: 192 edge-slices x 8 row-ranges = 1536 blocks.
// 256 thr + 25 KB LDS -> 6 blocks/CU (LDS-capped) = 1536 blocks exactly fills
// 256 CUs at 75% thread occupancy (vs 34% at the old 512x512 config).
#define NSL 192
#define SLICEB 6511           // ceil(NE / NSL); 6511*192 = 1250112 >= NE
#define RANGE 6250            // NN / 8 rows per range
#define CSTRIDE 50048         // padded row stride of cnt matrix

// bf16 helpers (RNE pack, cheap unpack)
__device__ __forceinline__ unsigned short f2b(float f) {
    unsigned int b = __builtin_bit_cast(unsigned int, f);
    b = (b + 0x7fffu + ((b >> 16) & 1u)) >> 16;
    return (unsigned short)b;
}
__device__ __forceinline__ float blo(unsigned int u) {
    return __builtin_bit_cast(float, u << 16);
}
__device__ __forceinline__ float bhi(unsigned int u) {
    return __builtin_bit_cast(float, u & 0xffff0000u);
}

// ---------------- fp32 -> bf16 pack of the embedding table ----------------
__global__ __launch_bounds__(256) void k_cvt(const float* __restrict__ in,
                                             unsigned short* __restrict__ out) {
    int t = blockIdx.x * blockDim.x + threadIdx.x;  // 8 elems per thread
    if (t >= NN * DIM / 8) return;
    const float4* p = (const float4*)in + t * 2;
    float4 a = p[0], b = p[1];
    ushort4 u0 = {f2b(a.x), f2b(a.y), f2b(a.z), f2b(a.w)};
    ushort4 u1 = {f2b(b.x), f2b(b.y), f2b(b.z), f2b(b.w)};
    ((ushort4*)out)[t * 2 + 0] = u0;
    ((ushort4*)out)[t * 2 + 1] = u1;
}

// ---------------- per-slice LDS histogram (NO global atomics) ----------------
// bid = (s&7) + 8*(rng + 8*(s>>3)) -> bid%8 == s%8: the 8 range-blocks of a
// slice land on one XCD, slice read into its L2 once (normal cached loads).
__global__ __launch_bounds__(256) void k_hist(const int* __restrict__ row,
                                              unsigned short* __restrict__ cnt) {
    __shared__ int h[RANGE];
    int bid = blockIdx.x;
    int s   = (bid & 7) | ((bid >> 6) << 3);
    int rng = (bid >> 3) & 7;
    int lo = rng * RANGE;
    int tid = threadIdx.x;
    for (int i = tid; i < RANGE; i += 256) h[i] = 0;
    __syncthreads();
    int beg = s * SLICEB;
    int end = beg + SLICEB;
    if (end > NE) end = NE;
    for (int e = beg + tid; e < end; e += 256) {
        int r = row[e] - lo;
        if ((unsigned)r < RANGE) atomicAdd(&h[r], 1);  // LDS atomic
    }
    __syncthreads();
    unsigned short* c = cnt + s * CSTRIDE + lo;
    for (int i = tid; i < RANGE; i += 256) c[i] = (unsigned short)h[i];
}

// ---------------- per-row scan over slices: cnt -> rel offsets, deg ----------------
__global__ __launch_bounds__(256) void k_rowscan(unsigned short* __restrict__ cnt,
                                                 int* __restrict__ deg) {
    int r = blockIdx.x * blockDim.x + threadIdx.x;
    if (r >= NN) return;
    int acc = 0;
    for (int s = 0; s < NSL; ++s) {
        int c = cnt[s * CSTRIDE + r];
        cnt[s * CSTRIDE + r] = (unsigned short)acc;  // exclusive within-row offset
        acc += c;
    }
    deg[r] = acc;
}

// ---------------- hierarchical exclusive scan over deg -> offs ----------------
__global__ __launch_bounds__(256) void k_scan_part(const int* __restrict__ deg,
                                                   int* __restrict__ partial) {
    __shared__ int s[256];
    int t = threadIdx.x;
    int i = blockIdx.x * 256 + t;
    s[t] = (i < NN) ? deg[i] : 0;
    __syncthreads();
    for (int off = 128; off > 0; off >>= 1) {
        if (t < off) s[t] += s[t + off];
        __syncthreads();
    }
    if (t == 0) partial[blockIdx.x] = s[0];
}

__global__ __launch_bounds__(256) void k_scan_top(int* __restrict__ partial) {
    __shared__ int s[256];
    int t = threadIdx.x;
    int v = (t < NPARTS) ? partial[t] : 0;
    s[t] = v;
    __syncthreads();
    for (int off = 1; off < 256; off <<= 1) {
        int x = (t >= off) ? s[t - off] : 0;
        __syncthreads();
        s[t] += x;
        __syncthreads();
    }
    if (t < NPARTS) partial[t] = s[t] - v;
}

__global__ __launch_bounds__(256) void k_scan_final(const int* __restrict__ deg,
                                                    const int* __restrict__ partial,
                                                    int* __restrict__ offs) {
    __shared__ int s[256];
    int t = threadIdx.x;
    int i = blockIdx.x * 256 + t;
    int v = (i < NN) ? deg[i] : 0;
    s[t] = v;
    __syncthreads();
    for (int off = 1; off < 256; off <<= 1) {
        int x = (t >= off) ? s[t - off] : 0;
        __syncthreads();
        s[t] += x;
        __syncthreads();
    }
    int excl = s[t] - v;
    if (i <= NN) offs[i] = partial[blockIdx.x] + excl;  // offs[NN] = NE
}

// ---------------- CSR fill via LDS cursor (NO global atomics) ----------------
// bid -> s = bid>>3, rng = bid&7 (bid%8 == rng): all 192 blocks writing a
// range's 625 KB csr region run on ONE XCD -> dirty lines accumulate in its
// L2, evict as full lines (r15: WRITE 48->4.9 MB). NT loads keep the edge
// stream out of L2/L3 so it can't evict the dirty csr lines (r14 lesson);
// the nt-HBM read latency (r15's serial wall) is hidden by 6 blocks/CU
// (75% occupancy, vs 34% at the old 512-block grid).
__global__ __launch_bounds__(256) void k_fillb(const int* __restrict__ row,
                                               const int* __restrict__ col,
                                               const int* __restrict__ offs,
                                               const unsigned short* __restrict__ cnt,
                                               int* __restrict__ csr) {
    __shared__ int cur[RANGE];
    int bid = blockIdx.x;
    int s   = bid >> 3;
    int rng = bid & 7;
    int lo = rng * RANGE;
    int tid = threadIdx.x;
    const unsigned short* c = cnt + s * CSTRIDE + lo;
    const int* o = offs + lo;
    for (int i = tid; i < RANGE; i += 256) cur[i] = o[i] + c[i];
    __syncthreads();
    int beg = s * SLICEB;
    int end = beg + SLICEB;
    if (end > NE) end = NE;
    for (int e = beg + tid; e < end; e += 256) {
        int r = __builtin_nontemporal_load(&row[e]) - lo;  // nt: don't evict csr
        if ((unsigned)r < RANGE) {
            int pos = atomicAdd(&cur[r], 1);  // LDS atomic
            csr[pos] = __builtin_nontemporal_load(&col[e]);
        }
    }
}

// ---------------- one propagation layer (bf16 gather, fp32 accum) ----------------
// 4 nodes per wave: lane>>4 = node in wave, lane&15 = feature-quad (uint2 load).
template <int PHASE>
__global__ __launch_bounds__(256) void k_layer(const unsigned short* __restrict__ xin16,
                                               const float* __restrict__ emb,
                                               unsigned short* __restrict__ xout16,
                                               float* __restrict__ out,
                                               const int* __restrict__ offs,
                                               const int* __restrict__ csr) {
    int wid = (blockIdx.x * blockDim.x + threadIdx.x) >> 6;
    int lane = threadIdx.x & 63;
    int sub = lane >> 4;    // node within wave (0..3)
    int sl = lane & 15;     // feature-quad index (0..15)
    int n = 4 * wid + sub;
    if (n >= NN) return;
    int beg = offs[n];
    int end = offs[n + 1];
    const unsigned short* xq = xin16 + sl * 4;

    float a0 = 0.f, a1 = 0.f, a2 = 0.f, a3 = 0.f;
    float b0 = 0.f, b1 = 0.f, b2 = 0.f, b3 = 0.f;
    int e = beg;
    for (; e + 8 <= end; e += 8) {
        int c0 = csr[e + 0], c1 = csr[e + 1], c2 = csr[e + 2], c3 = csr[e + 3];
        int c4 = csr[e + 4], c5 = csr[e + 5], c6 = csr[e + 6], c7 = csr[e + 7];
        uint2 u0 = *(const uint2*)(xq + c0 * DIM);
        uint2 u1 = *(const uint2*)(xq + c1 * DIM);
        uint2 u2 = *(const uint2*)(xq + c2 * DIM);
        uint2 u3 = *(const uint2*)(xq + c3 * DIM);
        uint2 u4 = *(const uint2*)(xq + c4 * DIM);
        uint2 u5 = *(const uint2*)(xq + c5 * DIM);
        uint2 u6 = *(const uint2*)(xq + c6 * DIM);
        uint2 u7 = *(const uint2*)(xq + c7 * DIM);
        a0 += blo(u0.x) + blo(u4.x);  b0 += blo(u1.x) + blo(u5.x);
        a1 += bhi(u0.x) + bhi(u4.x);  b1 += bhi(u1.x) + bhi(u5.x);
        a2 += blo(u0.y) + blo(u4.y);  b2 += blo(u1.y) + blo(u5.y);
        a3 += bhi(u0.y) + bhi(u4.y);  b3 += bhi(u1.y) + bhi(u5.y);
        a0 += blo(u2.x) + blo(u6.x);  b0 += blo(u3.x) + blo(u7.x);
        a1 += bhi(u2.x) + bhi(u6.x);  b1 += bhi(u3.x) + bhi(u7.x);
        a2 += blo(u2.y) + blo(u6.y);  b2 += blo(u3.y) + blo(u7.y);
        a3 += bhi(u2.y) + bhi(u6.y);  b3 += bhi(u3.y) + bhi(u7.y);
    }
    for (; e < end; ++e) {
        uint2 u = *(const uint2*)(xq + csr[e] * DIM);
        a0 += blo(u.x);
        a1 += bhi(u.x);
        a2 += blo(u.y);
        a3 += bhi(u.y);
    }

    int d = end - beg;
    float inv = (d > 0) ? 1.0f / (float)d : 0.0f;
    float v0 = (a0 + b0) * inv;
    float v1 = (a1 + b1) * inv;
    float v2 = (a2 + b2) * inv;
    float v3 = (a3 + b3) * inv;

    int o = n * DIM + sl * 4;
    if (PHASE == 0) {
        float4 ev = *(const float4*)(emb + o);
        float4 ov = {0.25f * (ev.x + v0), 0.25f * (ev.y + v1),
                     0.25f * (ev.z + v2), 0.25f * (ev.w + v3)};
        *(float4*)(out + o) = ov;
        uint2 pk = {(unsigned int)f2b(v0) | ((unsigned int)f2b(v1) << 16),
                    (unsigned int)f2b(v2) | ((unsigned int)f2b(v3) << 16)};
        *(uint2*)(xout16 + o) = pk;
    } else if (PHASE == 1) {
        float4 cur = *(const float4*)(out + o);
        cur.x += 0.25f * v0;
        cur.y += 0.25f * v1;
        cur.z += 0.25f * v2;
        cur.w += 0.25f * v3;
        *(float4*)(out + o) = cur;
        uint2 pk = {(unsigned int)f2b(v0) | ((unsigned int)f2b(v1) << 16),
                    (unsigned int)f2b(v2) | ((unsigned int)f2b(v3) << 16)};
        *(uint2*)(xout16 + o) = pk;
    } else {
        float4 cur = *(const float4*)(out + o);
        cur.x += 0.25f * v0;
        cur.y += 0.25f * v1;
        cur.z += 0.25f * v2;
        cur.w += 0.25f * v3;
        *(float4*)(out + o) = cur;
    }
}

extern "C" void kernel_launch(void* const* d_in, const int* in_sizes, int n_in,
                              void* d_out, int out_size, void* d_ws, size_t ws_size,
                              hipStream_t stream) {
    const int* edge = (const int*)d_in[0];
    const int* row = edge;        // edge_index[0]
    const int* col = edge + NE;   // edge_index[1]
    const float* emb = (const float*)d_in[1];
    float* out = (float*)d_out;

    // workspace layout (~44 MB of the 256 MB d_ws)
    int* deg    = (int*)d_ws;                                // 50048 ints
    int* offs   = deg + 50048;                               // 50112 ints
    int* partial= offs + 50112;                              // 256 ints
    int* csr    = partial + 256;                             // 1250048 ints
    unsigned short* cnt = (unsigned short*)(csr + 1250048);  // 192*50048 ushort (19.2MB)
    unsigned short* x0  = cnt + (size_t)NSL * CSTRIDE;       // 3.2M ushort
    unsigned short* xa  = x0 + NN * DIM;
    unsigned short* xb  = xa + NN * DIM;

    k_cvt       <<<(NN * DIM / 8 + 255) / 256, 256, 0, stream>>>(emb, x0);
    k_hist      <<<NSL * 8, 256, 0, stream>>>(row, cnt);
    k_rowscan   <<<NPARTS, 256, 0, stream>>>(cnt, deg);
    k_scan_part <<<NPARTS, 256, 0, stream>>>(deg, partial);
    k_scan_top  <<<1, 256, 0, stream>>>(partial);
    k_scan_final<<<NPARTS, 256, 0, stream>>>(deg, partial, offs);
    k_fillb     <<<NSL * 8, 256, 0, stream>>>(row, col, offs, cnt, csr);

    // 4 nodes per wave: 12500 waves -> 3125 blocks of 256
    int layer_blocks = (NN / 4 * 64) / 256;  // 3125
    k_layer<0><<<layer_blocks, 256, 0, stream>>>(x0, emb, xa, out, offs, csr);
    k_layer<1><<<layer_blocks, 256, 0, stream>>>(xa, nullptr, xb, out, offs, csr);
    k_layer<2><<<layer_blocks, 256, 0, stream>>>(xb, nullptr, nullptr, out, offs, csr);
}

// Round 17
// 143.000 us; speedup vs baseline: 1.1903x; 1.1542x over previous
//
#include <hip/hip_runtime.h>

#define NN 50000
#define DIM 64
#define NE 1250000
#define NPARTS 196  // ceil(50000/256)

// ---- counting-sort CSR build: 64 edge-slices x 8 row-ranges = 512 blocks
//      of 1024 threads, 25 KB LDS -> 2 blocks/CU (thread-capped) on 256 CUs
//      = 100% thread occupancy with exactly 512 blocks.
#define NSL 64
#define SLICEB 19532          // ceil(NE / NSL); 19532*64 = 1250048 >= NE
#define RANGE 6250            // NN / 8 rows per range
#define CSTRIDE 50048         // padded row stride of cnt matrix

// bf16 helpers (RNE pack, cheap unpack)
__device__ __forceinline__ unsigned short f2b(float f) {
    unsigned int b = __builtin_bit_cast(unsigned int, f);
    b = (b + 0x7fffu + ((b >> 16) & 1u)) >> 16;
    return (unsigned short)b;
}
__device__ __forceinline__ float blo(unsigned int u) {
    return __builtin_bit_cast(float, u << 16);
}
__device__ __forceinline__ float bhi(unsigned int u) {
    return __builtin_bit_cast(float, u & 0xffff0000u);
}

// ---------------- fp32 -> bf16 pack of the embedding table ----------------
__global__ __launch_bounds__(256) void k_cvt(const float* __restrict__ in,
                                             unsigned short* __restrict__ out) {
    int t = blockIdx.x * blockDim.x + threadIdx.x;  // 8 elems per thread
    if (t >= NN * DIM / 8) return;
    const float4* p = (const float4*)in + t * 2;
    float4 a = p[0], b = p[1];
    ushort4 u0 = {f2b(a.x), f2b(a.y), f2b(a.z), f2b(a.w)};
    ushort4 u1 = {f2b(b.x), f2b(b.y), f2b(b.z), f2b(b.w)};
    ((ushort4*)out)[t * 2 + 0] = u0;
    ((ushort4*)out)[t * 2 + 1] = u1;
}

// ---------------- per-slice LDS histogram (NO global atomics) ----------------
// bid -> slice s = (bid&7)|((bid>>6)<<3), rng = (bid>>3)&7.
// bid%8 == s%8 -> same-slice blocks on one XCD: slice read into L2 once.
__global__ __launch_bounds__(1024) void k_hist(const int* __restrict__ row,
                                               unsigned short* __restrict__ cnt) {
    __shared__ int h[RANGE];
    int bid = blockIdx.x;
    int s   = (bid & 7) | ((bid >> 6) << 3);
    int rng = (bid >> 3) & 7;
    int lo = rng * RANGE;
    int tid = threadIdx.x;
    for (int i = tid; i < RANGE; i += 1024) h[i] = 0;
    __syncthreads();
    int beg = s * SLICEB;
    int end = beg + SLICEB;
    if (end > NE) end = NE;
    for (int e = beg + tid; e < end; e += 1024) {
        int r = row[e] - lo;
        if ((unsigned)r < RANGE) atomicAdd(&h[r], 1);  // LDS atomic
    }
    __syncthreads();
    unsigned short* c = cnt + s * CSTRIDE + lo;
    for (int i = tid; i < RANGE; i += 1024) c[i] = (unsigned short)h[i];
}

// ---------------- per-row scan over slices: cnt -> rel offsets, deg ----------------
__global__ __launch_bounds__(256) void k_rowscan(unsigned short* __restrict__ cnt,
                                                 int* __restrict__ deg) {
    int r = blockIdx.x * blockDim.x + threadIdx.x;
    if (r >= NN) return;
    int acc = 0;
#pragma unroll
    for (int s = 0; s < NSL; ++s) {
        int c = cnt[s * CSTRIDE + r];
        cnt[s * CSTRIDE + r] = (unsigned short)acc;  // exclusive within-row offset
        acc += c;
    }
    deg[r] = acc;
}

// ---------------- hierarchical exclusive scan over deg -> offs ----------------
__global__ __launch_bounds__(256) void k_scan_part(const int* __restrict__ deg,
                                                   int* __restrict__ partial) {
    __shared__ int s[256];
    int t = threadIdx.x;
    int i = blockIdx.x * 256 + t;
    s[t] = (i < NN) ? deg[i] : 0;
    __syncthreads();
    for (int off = 128; off > 0; off >>= 1) {
        if (t < off) s[t] += s[t + off];
        __syncthreads();
    }
    if (t == 0) partial[blockIdx.x] = s[0];
}

__global__ __launch_bounds__(256) void k_scan_top(int* __restrict__ partial) {
    __shared__ int s[256];
    int t = threadIdx.x;
    int v = (t < NPARTS) ? partial[t] : 0;
    s[t] = v;
    __syncthreads();
    for (int off = 1; off < 256; off <<= 1) {
        int x = (t >= off) ? s[t - off] : 0;
        __syncthreads();
        s[t] += x;
        __syncthreads();
    }
    if (t < NPARTS) partial[t] = s[t] - v;
}

__global__ __launch_bounds__(256) void k_scan_final(const int* __restrict__ deg,
                                                    const int* __restrict__ partial,
                                                    int* __restrict__ offs) {
    __shared__ int s[256];
    int t = threadIdx.x;
    int i = blockIdx.x * 256 + t;
    int v = (i < NN) ? deg[i] : 0;
    s[t] = v;
    __syncthreads();
    for (int off = 1; off < 256; off <<= 1) {
        int x = (t >= off) ? s[t - off] : 0;
        __syncthreads();
        s[t] += x;
        __syncthreads();
    }
    int excl = s[t] - v;
    if (i <= NN) offs[i] = partial[blockIdx.x] + excl;  // offs[NN] = NE
}

// ---------------- CSR fill via LDS cursor (NO global atomics) ----------------
// bid -> s = bid>>3, rng = bid&7 (bid%8 == rng): all 64 blocks writing a
// range's 625 KB csr region run on ONE XCD -> dirty lines accumulate in its
// L2 and evict as full lines (proven: WRITE 48->4.9 MB). NT loads keep the
// edge stream from evicting the dirty csr lines (r14 lesson). The nt read
// latency (r15/r16 wall) is hidden by 100% thread occupancy: 1024-thr
// blocks, 2/CU, 19 iterations/thread.
__global__ __launch_bounds__(1024) void k_fillb(const int* __restrict__ row,
                                                const int* __restrict__ col,
                                                const int* __restrict__ offs,
                                                const unsigned short* __restrict__ cnt,
                                                int* __restrict__ csr) {
    __shared__ int cur[RANGE];
    int bid = blockIdx.x;
    int s   = bid >> 3;
    int rng = bid & 7;
    int lo = rng * RANGE;
    int tid = threadIdx.x;
    const unsigned short* c = cnt + s * CSTRIDE + lo;
    const int* o = offs + lo;
    for (int i = tid; i < RANGE; i += 1024) cur[i] = o[i] + c[i];
    __syncthreads();
    int beg = s * SLICEB;
    int end = beg + SLICEB;
    if (end > NE) end = NE;
    for (int e = beg + tid; e < end; e += 1024) {
        int r = __builtin_nontemporal_load(&row[e]) - lo;  // nt: don't evict csr
        if ((unsigned)r < RANGE) {
            int pos = atomicAdd(&cur[r], 1);  // LDS atomic
            csr[pos] = __builtin_nontemporal_load(&col[e]);
        }
    }
}

// ---------------- one propagation layer (bf16 gather, fp32 accum) ----------------
// 8 nodes per wave: lane>>3 = node in wave, lane&7 = feature-octet.
// Each lane loads uint4 (8 bf16, 16 B) -> one vector-mem instruction fetches
// 8 rows (1 KB); gather instruction count drops ~1.8x net of divergence
// (layers are issue-rate-bound: r10->r11->r12 all tracked instruction count).
template <int PHASE>
__global__ __launch_bounds__(256) void k_layer(const unsigned short* __restrict__ xin16,
                                               const float* __restrict__ emb,
                                               unsigned short* __restrict__ xout16,
                                               float* __restrict__ out,
                                               const int* __restrict__ offs,
                                               const int* __restrict__ csr) {
    int wid = (blockIdx.x * blockDim.x + threadIdx.x) >> 6;
    int lane = threadIdx.x & 63;
    int sub = lane >> 3;    // node within wave (0..7)
    int sl = lane & 7;      // feature-octet index (0..7)
    int n = 8 * wid + sub;
    if (n >= NN) return;
    int beg = offs[n];
    int end = offs[n + 1];
    const unsigned short* xq = xin16 + sl * 8;  // + c*DIM per neighbor, 16B-aligned

    // two accumulator banks (even/odd edges) x 8 features
    float a0 = 0.f, a1 = 0.f, a2 = 0.f, a3 = 0.f, a4 = 0.f, a5 = 0.f, a6 = 0.f, a7 = 0.f;
    float b0 = 0.f, b1 = 0.f, b2 = 0.f, b3 = 0.f, b4 = 0.f, b5 = 0.f, b6 = 0.f, b7 = 0.f;
    int e = beg;
    for (; e + 8 <= end; e += 8) {
        int c0 = csr[e + 0], c1 = csr[e + 1], c2 = csr[e + 2], c3 = csr[e + 3];
        int c4 = csr[e + 4], c5 = csr[e + 5], c6 = csr[e + 6], c7 = csr[e + 7];
        uint4 u0 = *(const uint4*)(xq + c0 * DIM);
        uint4 u1 = *(const uint4*)(xq + c1 * DIM);
        uint4 u2 = *(const uint4*)(xq + c2 * DIM);
        uint4 u3 = *(const uint4*)(xq + c3 * DIM);
        uint4 u4 = *(const uint4*)(xq + c4 * DIM);
        uint4 u5 = *(const uint4*)(xq + c5 * DIM);
        uint4 u6 = *(const uint4*)(xq + c6 * DIM);
        uint4 u7 = *(const uint4*)(xq + c7 * DIM);
        a0 += blo(u0.x) + blo(u2.x);  b0 += blo(u1.x) + blo(u3.x);
        a1 += bhi(u0.x) + bhi(u2.x);  b1 += bhi(u1.x) + bhi(u3.x);
        a2 += blo(u0.y) + blo(u2.y);  b2 += blo(u1.y) + blo(u3.y);
        a3 += bhi(u0.y) + bhi(u2.y);  b3 += bhi(u1.y) + bhi(u3.y);
        a4 += blo(u0.z) + blo(u2.z);  b4 += blo(u1.z) + blo(u3.z);
        a5 += bhi(u0.z) + bhi(u2.z);  b5 += bhi(u1.z) + bhi(u3.z);
        a6 += blo(u0.w) + blo(u2.w);  b6 += blo(u1.w) + blo(u3.w);
        a7 += bhi(u0.w) + bhi(u2.w);  b7 += bhi(u1.w) + bhi(u3.w);
        a0 += blo(u4.x) + blo(u6.x);  b0 += blo(u5.x) + blo(u7.x);
        a1 += bhi(u4.x) + bhi(u6.x);  b1 += bhi(u5.x) + bhi(u7.x);
        a2 += blo(u4.y) + blo(u6.y);  b2 += blo(u5.y) + blo(u7.y);
        a3 += bhi(u4.y) + bhi(u6.y);  b3 += bhi(u5.y) + bhi(u7.y);
        a4 += blo(u4.z) + blo(u6.z);  b4 += blo(u5.z) + blo(u7.z);
        a5 += bhi(u4.z) + bhi(u6.z);  b5 += bhi(u5.z) + bhi(u7.z);
        a6 += blo(u4.w) + blo(u6.w);  b6 += blo(u5.w) + blo(u7.w);
        a7 += bhi(u4.w) + bhi(u6.w);  b7 += bhi(u5.w) + bhi(u7.w);
    }
    for (; e < end; ++e) {
        uint4 u = *(const uint4*)(xq + csr[e] * DIM);
        a0 += blo(u.x);
        a1 += bhi(u.x);
        a2 += blo(u.y);
        a3 += bhi(u.y);
        a4 += blo(u.z);
        a5 += bhi(u.z);
        a6 += blo(u.w);
        a7 += bhi(u.w);
    }

    int d = end - beg;
    float inv = (d > 0) ? 1.0f / (float)d : 0.0f;
    float v0 = (a0 + b0) * inv;
    float v1 = (a1 + b1) * inv;
    float v2 = (a2 + b2) * inv;
    float v3 = (a3 + b3) * inv;
    float v4 = (a4 + b4) * inv;
    float v5 = (a5 + b5) * inv;
    float v6 = (a6 + b6) * inv;
    float v7 = (a7 + b7) * inv;

    int o = n * DIM + sl * 8;
    uint4 pk = {(unsigned int)f2b(v0) | ((unsigned int)f2b(v1) << 16),
                (unsigned int)f2b(v2) | ((unsigned int)f2b(v3) << 16),
                (unsigned int)f2b(v4) | ((unsigned int)f2b(v5) << 16),
                (unsigned int)f2b(v6) | ((unsigned int)f2b(v7) << 16)};
    if (PHASE == 0) {
        float4 e0 = *(const float4*)(emb + o);
        float4 e1 = *(const float4*)(emb + o + 4);
        float4 o0 = {0.25f * (e0.x + v0), 0.25f * (e0.y + v1),
                     0.25f * (e0.z + v2), 0.25f * (e0.w + v3)};
        float4 o1 = {0.25f * (e1.x + v4), 0.25f * (e1.y + v5),
                     0.25f * (e1.z + v6), 0.25f * (e1.w + v7)};
        *(float4*)(out + o) = o0;
        *(float4*)(out + o + 4) = o1;
        *(uint4*)(xout16 + o) = pk;
    } else if (PHASE == 1) {
        float4 c0 = *(const float4*)(out + o);
        float4 c1 = *(const float4*)(out + o + 4);
        c0.x += 0.25f * v0; c0.y += 0.25f * v1; c0.z += 0.25f * v2; c0.w += 0.25f * v3;
        c1.x += 0.25f * v4; c1.y += 0.25f * v5; c1.z += 0.25f * v6; c1.w += 0.25f * v7;
        *(float4*)(out + o) = c0;
        *(float4*)(out + o + 4) = c1;
        *(uint4*)(xout16 + o) = pk;
    } else {
        float4 c0 = *(const float4*)(out + o);
        float4 c1 = *(const float4*)(out + o + 4);
        c0.x += 0.25f * v0; c0.y += 0.25f * v1; c0.z += 0.25f * v2; c0.w += 0.25f * v3;
        c1.x += 0.25f * v4; c1.y += 0.25f * v5; c1.z += 0.25f * v6; c1.w += 0.25f * v7;
        *(float4*)(out + o) = c0;
        *(float4*)(out + o + 4) = c1;
    }
}

extern "C" void kernel_launch(void* const* d_in, const int* in_sizes, int n_in,
                              void* d_out, int out_size, void* d_ws, size_t ws_size,
                              hipStream_t stream) {
    const int* edge = (const int*)d_in[0];
    const int* row = edge;        // edge_index[0]
    const int* col = edge + NE;   // edge_index[1]
    const float* emb = (const float*)d_in[1];
    float* out = (float*)d_out;

    // workspace layout (~31 MB)
    int* deg    = (int*)d_ws;                                // 50048 ints
    int* offs   = deg + 50048;                               // 50112 ints
    int* partial= offs + 50112;                              // 256 ints
    int* csr    = partial + 256;                             // 1250048 ints
    unsigned short* cnt = (unsigned short*)(csr + 1250048);  // 64*50048 ushort (6.4MB)
    unsigned short* x0  = cnt + (size_t)NSL * CSTRIDE;       // 3.2M ushort
    unsigned short* xa  = x0 + NN * DIM;
    unsigned short* xb  = xa + NN * DIM;

    k_cvt       <<<(NN * DIM / 8 + 255) / 256, 256, 0, stream>>>(emb, x0);
    k_hist      <<<NSL * 8, 1024, 0, stream>>>(row, cnt);
    k_rowscan   <<<NPARTS, 256, 0, stream>>>(cnt, deg);
    k_scan_part <<<NPARTS, 256, 0, stream>>>(deg, partial);
    k_scan_top  <<<1, 256, 0, stream>>>(partial);
    k_scan_final<<<NPARTS, 256, 0, stream>>>(deg, partial, offs);
    k_fillb     <<<NSL * 8, 1024, 0, stream>>>(row, col, offs, cnt, csr);

    // 8 nodes per wave: 6250 waves -> 1563 blocks of 256 (guard in-kernel)
    int layer_blocks = 1563;
    k_layer<0><<<layer_blocks, 256, 0, stream>>>(x0, emb, xa, out, offs, csr);
    k_layer<1><<<layer_blocks, 256, 0, stream>>>(xa, nullptr, xb, out, offs, csr);
    k_layer<2><<<layer_blocks, 256, 0, stream>>>(xb, nullptr, nullptr, out, offs, csr);
}

// Round 18
// 136.063 us; speedup vs baseline: 1.2510x; 1.0510x over previous
//
#include <hip/hip_runtime.h>

#define NN 50000
#define DIM 64
#define NE 1250000
#define NPARTS 196  // ceil(50000/256)

// ---- counting-sort CSR build: 64 edge-slices x 8 row-ranges = 512 blocks
//      of 1024 threads, 25 KB LDS -> 2 blocks/CU = 100% thread occupancy.
#define NSL 64
#define SLICEB 19532          // ceil(NE / NSL); 19532*64 = 1250048 >= NE
#define RANGE 6250            // NN / 8 rows per range
#define CSTRIDE 50048         // padded row stride of cnt matrix

// bf16 helpers (RNE pack, cheap unpack)
__device__ __forceinline__ unsigned short f2b(float f) {
    unsigned int b = __builtin_bit_cast(unsigned int, f);
    b = (b + 0x7fffu + ((b >> 16) & 1u)) >> 16;
    return (unsigned short)b;
}
__device__ __forceinline__ float blo(unsigned int u) {
    return __builtin_bit_cast(float, u << 16);
}
__device__ __forceinline__ float bhi(unsigned int u) {
    return __builtin_bit_cast(float, u & 0xffff0000u);
}

// ---------------- fp32 -> bf16 pack of the embedding table ----------------
__global__ __launch_bounds__(256) void k_cvt(const float* __restrict__ in,
                                             unsigned short* __restrict__ out) {
    int t = blockIdx.x * blockDim.x + threadIdx.x;  // 8 elems per thread
    if (t >= NN * DIM / 8) return;
    const float4* p = (const float4*)in + t * 2;
    float4 a = p[0], b = p[1];
    ushort4 u0 = {f2b(a.x), f2b(a.y), f2b(a.z), f2b(a.w)};
    ushort4 u1 = {f2b(b.x), f2b(b.y), f2b(b.z), f2b(b.w)};
    ((ushort4*)out)[t * 2 + 0] = u0;
    ((ushort4*)out)[t * 2 + 1] = u1;
}

// ---------------- per-slice LDS histogram (NO global atomics) ----------------
// bid -> slice s = (bid&7)|((bid>>6)<<3), rng = (bid>>3)&7.
// bid%8 == s%8 -> same-slice blocks on one XCD: slice read into L2 once.
__global__ __launch_bounds__(1024) void k_hist(const int* __restrict__ row,
                                               unsigned short* __restrict__ cnt) {
    __shared__ int h[RANGE];
    int bid = blockIdx.x;
    int s   = (bid & 7) | ((bid >> 6) << 3);
    int rng = (bid >> 3) & 7;
    int lo = rng * RANGE;
    int tid = threadIdx.x;
    for (int i = tid; i < RANGE; i += 1024) h[i] = 0;
    __syncthreads();
    int beg = s * SLICEB;
    int end = beg + SLICEB;
    if (end > NE) end = NE;
    for (int e = beg + tid; e < end; e += 1024) {
        int r = row[e] - lo;
        if ((unsigned)r < RANGE) atomicAdd(&h[r], 1);  // LDS atomic
    }
    __syncthreads();
    unsigned short* c = cnt + s * CSTRIDE + lo;
    for (int i = tid; i < RANGE; i += 1024) c[i] = (unsigned short)h[i];
}

// ---------------- rowscan + partial-sum fusion ----------------
// per-row scan over slices (cnt -> within-row exclusive offsets, deg) AND
// block-level deg reduction into partial[] (replaces k_scan_part).
__global__ __launch_bounds__(256) void k_rowscan(unsigned short* __restrict__ cnt,
                                                 int* __restrict__ deg,
                                                 int* __restrict__ partial) {
    __shared__ int sred[256];
    int t = threadIdx.x;
    int r = blockIdx.x * 256 + t;
    int acc = 0;
    if (r < NN) {
#pragma unroll
        for (int s = 0; s < NSL; ++s) {
            int c = cnt[s * CSTRIDE + r];
            cnt[s * CSTRIDE + r] = (unsigned short)acc;  // exclusive within-row offset
            acc += c;
        }
        deg[r] = acc;
    }
    sred[t] = acc;
    __syncthreads();
    for (int off = 128; off > 0; off >>= 1) {
        if (t < off) sred[t] += sred[t + off];
        __syncthreads();
    }
    if (t == 0) partial[blockIdx.x] = sred[0];
}

// ---------------- scan of block partials ----------------
__global__ __launch_bounds__(256) void k_scan_top(int* __restrict__ partial) {
    __shared__ int s[256];
    int t = threadIdx.x;
    int v = (t < NPARTS) ? partial[t] : 0;
    s[t] = v;
    __syncthreads();
    for (int off = 1; off < 256; off <<= 1) {
        int x = (t >= off) ? s[t - off] : 0;
        __syncthreads();
        s[t] += x;
        __syncthreads();
    }
    if (t < NPARTS) partial[t] = s[t] - v;
}

__global__ __launch_bounds__(256) void k_scan_final(const int* __restrict__ deg,
                                                    const int* __restrict__ partial,
                                                    int* __restrict__ offs) {
    __shared__ int s[256];
    int t = threadIdx.x;
    int i = blockIdx.x * 256 + t;
    int v = (i < NN) ? deg[i] : 0;
    s[t] = v;
    __syncthreads();
    for (int off = 1; off < 256; off <<= 1) {
        int x = (t >= off) ? s[t - off] : 0;
        __syncthreads();
        s[t] += x;
        __syncthreads();
    }
    int excl = s[t] - v;
    if (i <= NN) offs[i] = partial[blockIdx.x] + excl;  // offs[NN] = NE
}

// ---------------- CSR fill via LDS cursor (NO global atomics) ----------------
// bid -> s = bid>>3, rng = bid&7 (bid%8 == rng): all 64 blocks writing a
// range's csr region run on ONE XCD -> full-line evictions (WRITE 48->4.9MB).
// NT loads keep the edge stream from evicting dirty csr lines. 4-deep row
// batching: 4 independent nt loads in flight per thread (the nt-HBM latency
// chain was the r15/r16 wall).
__global__ __launch_bounds__(1024) void k_fillb(const int* __restrict__ row,
                                                const int* __restrict__ col,
                                                const int* __restrict__ offs,
                                                const unsigned short* __restrict__ cnt,
                                                int* __restrict__ csr) {
    __shared__ int cur[RANGE];
    int bid = blockIdx.x;
    int s   = bid >> 3;
    int rng = bid & 7;
    int lo = rng * RANGE;
    int tid = threadIdx.x;
    const unsigned short* c = cnt + s * CSTRIDE + lo;
    const int* o = offs + lo;
    for (int i = tid; i < RANGE; i += 1024) cur[i] = o[i] + c[i];
    __syncthreads();
    int beg = s * SLICEB;
    int end = beg + SLICEB;
    if (end > NE) end = NE;
    int e = beg + tid;
    for (; e + 3 * 1024 < end; e += 4 * 1024) {
        int r0 = __builtin_nontemporal_load(&row[e]) - lo;
        int r1 = __builtin_nontemporal_load(&row[e + 1024]) - lo;
        int r2 = __builtin_nontemporal_load(&row[e + 2048]) - lo;
        int r3 = __builtin_nontemporal_load(&row[e + 3072]) - lo;
        if ((unsigned)r0 < RANGE) {
            int pos = atomicAdd(&cur[r0], 1);
            csr[pos] = __builtin_nontemporal_load(&col[e]);
        }
        if ((unsigned)r1 < RANGE) {
            int pos = atomicAdd(&cur[r1], 1);
            csr[pos] = __builtin_nontemporal_load(&col[e + 1024]);
        }
        if ((unsigned)r2 < RANGE) {
            int pos = atomicAdd(&cur[r2], 1);
            csr[pos] = __builtin_nontemporal_load(&col[e + 2048]);
        }
        if ((unsigned)r3 < RANGE) {
            int pos = atomicAdd(&cur[r3], 1);
            csr[pos] = __builtin_nontemporal_load(&col[e + 3072]);
        }
    }
    for (; e < end; e += 1024) {
        int r = __builtin_nontemporal_load(&row[e]) - lo;
        if ((unsigned)r < RANGE) {
            int pos = atomicAdd(&cur[r], 1);
            csr[pos] = __builtin_nontemporal_load(&col[e]);
        }
    }
}

// ---------------- one propagation layer (bf16 gather, fp32 accum) ----------------
// 8 nodes per wave: lane>>3 = node in wave, lane&7 = feature-octet (uint4).
// out-accumulation DEFERRED to the last phase (saves ~38 MB of out r/w):
// PHASE 0: x0 -> xa (store bf16 only)
// PHASE 1: xa -> xb (store bf16 only)
// PHASE 2: xb -> v; out = 0.25*(emb + xa + xb + v)  (single out pass)
template <int PHASE>
__global__ __launch_bounds__(256) void k_layer(const unsigned short* __restrict__ xin16,
                                               const float* __restrict__ emb,
                                               const unsigned short* __restrict__ xa16,
                                               unsigned short* __restrict__ xout16,
                                               float* __restrict__ out,
                                               const int* __restrict__ offs,
                                               const int* __restrict__ csr) {
    int wid = (blockIdx.x * blockDim.x + threadIdx.x) >> 6;
    int lane = threadIdx.x & 63;
    int sub = lane >> 3;    // node within wave (0..7)
    int sl = lane & 7;      // feature-octet index (0..7)
    int n = 8 * wid + sub;
    if (n >= NN) return;
    int beg = offs[n];
    int end = offs[n + 1];
    const unsigned short* xq = xin16 + sl * 8;  // + c*DIM per neighbor, 16B-aligned

    float a0 = 0.f, a1 = 0.f, a2 = 0.f, a3 = 0.f, a4 = 0.f, a5 = 0.f, a6 = 0.f, a7 = 0.f;
    float b0 = 0.f, b1 = 0.f, b2 = 0.f, b3 = 0.f, b4 = 0.f, b5 = 0.f, b6 = 0.f, b7 = 0.f;
    int e = beg;
    for (; e + 8 <= end; e += 8) {
        int c0 = csr[e + 0], c1 = csr[e + 1], c2 = csr[e + 2], c3 = csr[e + 3];
        int c4 = csr[e + 4], c5 = csr[e + 5], c6 = csr[e + 6], c7 = csr[e + 7];
        uint4 u0 = *(const uint4*)(xq + c0 * DIM);
        uint4 u1 = *(const uint4*)(xq + c1 * DIM);
        uint4 u2 = *(const uint4*)(xq + c2 * DIM);
        uint4 u3 = *(const uint4*)(xq + c3 * DIM);
        uint4 u4 = *(const uint4*)(xq + c4 * DIM);
        uint4 u5 = *(const uint4*)(xq + c5 * DIM);
        uint4 u6 = *(const uint4*)(xq + c6 * DIM);
        uint4 u7 = *(const uint4*)(xq + c7 * DIM);
        a0 += blo(u0.x) + blo(u2.x);  b0 += blo(u1.x) + blo(u3.x);
        a1 += bhi(u0.x) + bhi(u2.x);  b1 += bhi(u1.x) + bhi(u3.x);
        a2 += blo(u0.y) + blo(u2.y);  b2 += blo(u1.y) + blo(u3.y);
        a3 += bhi(u0.y) + bhi(u2.y);  b3 += bhi(u1.y) + bhi(u3.y);
        a4 += blo(u0.z) + blo(u2.z);  b4 += blo(u1.z) + blo(u3.z);
        a5 += bhi(u0.z) + bhi(u2.z);  b5 += bhi(u1.z) + bhi(u3.z);
        a6 += blo(u0.w) + blo(u2.w);  b6 += blo(u1.w) + blo(u3.w);
        a7 += bhi(u0.w) + bhi(u2.w);  b7 += bhi(u1.w) + bhi(u3.w);
        a0 += blo(u4.x) + blo(u6.x);  b0 += blo(u5.x) + blo(u7.x);
        a1 += bhi(u4.x) + bhi(u6.x);  b1 += bhi(u5.x) + bhi(u7.x);
        a2 += blo(u4.y) + blo(u6.y);  b2 += blo(u5.y) + blo(u7.y);
        a3 += bhi(u4.y) + bhi(u6.y);  b3 += bhi(u5.y) + bhi(u7.y);
        a4 += blo(u4.z) + blo(u6.z);  b4 += blo(u5.z) + blo(u7.z);
        a5 += bhi(u4.z) + bhi(u6.z);  b5 += bhi(u5.z) + bhi(u7.z);
        a6 += blo(u4.w) + blo(u6.w);  b6 += blo(u5.w) + blo(u7.w);
        a7 += bhi(u4.w) + bhi(u6.w);  b7 += bhi(u5.w) + bhi(u7.w);
    }
    for (; e < end; ++e) {
        uint4 u = *(const uint4*)(xq + csr[e] * DIM);
        a0 += blo(u.x);
        a1 += bhi(u.x);
        a2 += blo(u.y);
        a3 += bhi(u.y);
        a4 += blo(u.z);
        a5 += bhi(u.z);
        a6 += blo(u.w);
        a7 += bhi(u.w);
    }

    int d = end - beg;
    float inv = (d > 0) ? 1.0f / (float)d : 0.0f;
    float v0 = (a0 + b0) * inv;
    float v1 = (a1 + b1) * inv;
    float v2 = (a2 + b2) * inv;
    float v3 = (a3 + b3) * inv;
    float v4 = (a4 + b4) * inv;
    float v5 = (a5 + b5) * inv;
    float v6 = (a6 + b6) * inv;
    float v7 = (a7 + b7) * inv;

    int o = n * DIM + sl * 8;
    if (PHASE < 2) {
        uint4 pk = {(unsigned int)f2b(v0) | ((unsigned int)f2b(v1) << 16),
                    (unsigned int)f2b(v2) | ((unsigned int)f2b(v3) << 16),
                    (unsigned int)f2b(v4) | ((unsigned int)f2b(v5) << 16),
                    (unsigned int)f2b(v6) | ((unsigned int)f2b(v7) << 16)};
        *(uint4*)(xout16 + o) = pk;
    } else {
        // out = 0.25*(emb + xa + xb + v); xin16 == xb here, xa16 == xa
        float4 e0 = *(const float4*)(emb + o);
        float4 e1 = *(const float4*)(emb + o + 4);
        uint4 ua = *(const uint4*)(xa16 + o);
        uint4 ub = *(const uint4*)(xin16 + o);
        float4 o0, o1;
        o0.x = 0.25f * (e0.x + blo(ua.x) + blo(ub.x) + v0);
        o0.y = 0.25f * (e0.y + bhi(ua.x) + bhi(ub.x) + v1);
        o0.z = 0.25f * (e0.z + blo(ua.y) + blo(ub.y) + v2);
        o0.w = 0.25f * (e0.w + bhi(ua.y) + bhi(ub.y) + v3);
        o1.x = 0.25f * (e1.x + blo(ua.z) + blo(ub.z) + v4);
        o1.y = 0.25f * (e1.y + bhi(ua.z) + bhi(ub.z) + v5);
        o1.z = 0.25f * (e1.z + blo(ua.w) + blo(ub.w) + v6);
        o1.w = 0.25f * (e1.w + bhi(ua.w) + bhi(ub.w) + v7);
        *(float4*)(out + o) = o0;
        *(float4*)(out + o + 4) = o1;
    }
}

extern "C" void kernel_launch(void* const* d_in, const int* in_sizes, int n_in,
                              void* d_out, int out_size, void* d_ws, size_t ws_size,
                              hipStream_t stream) {
    const int* edge = (const int*)d_in[0];
    const int* row = edge;        // edge_index[0]
    const int* col = edge + NE;   // edge_index[1]
    const float* emb = (const float*)d_in[1];
    float* out = (float*)d_out;

    // workspace layout (~31 MB)
    int* deg    = (int*)d_ws;                                // 50048 ints
    int* offs   = deg + 50048;                               // 50112 ints
    int* partial= offs + 50112;                              // 256 ints
    int* csr    = partial + 256;                             // 1250048 ints
    unsigned short* cnt = (unsigned short*)(csr + 1250048);  // 64*50048 ushort (6.4MB)
    unsigned short* x0  = cnt + (size_t)NSL * CSTRIDE;       // 3.2M ushort
    unsigned short* xa  = x0 + NN * DIM;
    unsigned short* xb  = xa + NN * DIM;

    k_cvt       <<<(NN * DIM / 8 + 255) / 256, 256, 0, stream>>>(emb, x0);
    k_hist      <<<NSL * 8, 1024, 0, stream>>>(row, cnt);
    k_rowscan   <<<NPARTS, 256, 0, stream>>>(cnt, deg, partial);
    k_scan_top  <<<1, 256, 0, stream>>>(partial);
    k_scan_final<<<NPARTS, 256, 0, stream>>>(deg, partial, offs);
    k_fillb     <<<NSL * 8, 1024, 0, stream>>>(row, col, offs, cnt, csr);

    // 8 nodes per wave: 6250 waves -> 1563 blocks of 256 (guard in-kernel)
    int layer_blocks = 1563;
    k_layer<0><<<layer_blocks, 256, 0, stream>>>(x0, nullptr, nullptr, xa, nullptr, offs, csr);
    k_layer<1><<<layer_blocks, 256, 0, stream>>>(xa, nullptr, nullptr, xb, nullptr, offs, csr);
    k_layer<2><<<layer_blocks, 256, 0, stream>>>(xb, emb, xa, nullptr, out, offs, csr);
}

// Round 20
// 117.424 us; speedup vs baseline: 1.4495x; 1.1587x over previous
//
#include <hip/hip_runtime.h>
#include <hip/hip_fp8.h>

#define NN 50000
#define DIM 64
#define NE 1250000
#define NPARTS 196  // ceil(50000/256)

// ---- counting-sort CSR build: 64 edge-slices x 8 row-ranges = 512 blocks
//      of 1024 threads, 25 KB LDS -> 2 blocks/CU = 100% thread occupancy.
#define NSL 64
#define SLICEB 19532          // ceil(NE / NSL); 19532*64 = 1250048 >= NE
#define RANGE 6250            // NN / 8 rows per range
#define CSTRIDE 50048         // padded row stride of cnt matrix

typedef __attribute__((ext_vector_type(2))) float f32x2;

// bf16 helpers (RNE pack, cheap unpack)
__device__ __forceinline__ unsigned short f2b(float f) {
    unsigned int b = __builtin_bit_cast(unsigned int, f);
    b = (b + 0x7fffu + ((b >> 16) & 1u)) >> 16;
    return (unsigned short)b;
}
__device__ __forceinline__ float blo(unsigned int u) {
    return __builtin_bit_cast(float, u << 16);
}
__device__ __forceinline__ float bhi(unsigned int u) {
    return __builtin_bit_cast(float, u & 0xffff0000u);
}

// fp8 e4m3 (OCP) helpers — hardware cvt on gfx950, hip_fp8.h fallback.
// NOTE: builtin's word-select must be a CONSTANT -> template parameter.
template <bool HI>
__device__ __forceinline__ f32x2 dec2(unsigned int u) {
#if __has_builtin(__builtin_amdgcn_cvt_pk_f32_fp8)
    return __builtin_amdgcn_cvt_pk_f32_fp8(u, HI);
#else
    unsigned int b0 = HI ? ((u >> 16) & 0xff) : (u & 0xff);
    unsigned int b1 = HI ? ((u >> 24) & 0xff) : ((u >> 8) & 0xff);
    __hip_fp8_e4m3 t0, t1;
    t0.__x = (unsigned char)b0;
    t1.__x = (unsigned char)b1;
    f32x2 r;
    r[0] = (float)t0;
    r[1] = (float)t1;
    return r;
#endif
}
__device__ __forceinline__ unsigned int enc4(float v0, float v1, float v2, float v3) {
#if __has_builtin(__builtin_amdgcn_cvt_pk_fp8_f32)
    unsigned int r = 0;
    r = __builtin_amdgcn_cvt_pk_fp8_f32(v0, v1, r, false);
    r = __builtin_amdgcn_cvt_pk_fp8_f32(v2, v3, r, true);
    return r;
#else
    __hip_fp8_e4m3 t0(v0), t1(v1), t2(v2), t3(v3);
    return (unsigned int)t0.__x | ((unsigned int)t1.__x << 8) |
           ((unsigned int)t2.__x << 16) | ((unsigned int)t3.__x << 24);
#endif
}

// ---------------- fp32 emb -> fp8 gather mirror ----------------
__global__ __launch_bounds__(256) void k_cvt(const float* __restrict__ in,
                                             unsigned char* __restrict__ out8) {
    int t = blockIdx.x * blockDim.x + threadIdx.x;  // 8 elems per thread
    if (t >= NN * DIM / 8) return;
    const float4* p = (const float4*)in + t * 2;
    float4 a = p[0], b = p[1];
    uint2 pk;
    pk.x = enc4(a.x, a.y, a.z, a.w);
    pk.y = enc4(b.x, b.y, b.z, b.w);
    ((uint2*)out8)[t] = pk;
}

// ---------------- per-slice LDS histogram (NO global atomics) ----------------
// bid -> slice s = (bid&7)|((bid>>6)<<3), rng = (bid>>3)&7.
// bid%8 == s%8 -> same-slice blocks on one XCD: slice read into L2 once.
__global__ __launch_bounds__(1024) void k_hist(const int* __restrict__ row,
                                               unsigned short* __restrict__ cnt) {
    __shared__ int h[RANGE];
    int bid = blockIdx.x;
    int s   = (bid & 7) | ((bid >> 6) << 3);
    int rng = (bid >> 3) & 7;
    int lo = rng * RANGE;
    int tid = threadIdx.x;
    for (int i = tid; i < RANGE; i += 1024) h[i] = 0;
    __syncthreads();
    int beg = s * SLICEB;
    int end = beg + SLICEB;
    if (end > NE) end = NE;
    for (int e = beg + tid; e < end; e += 1024) {
        int r = row[e] - lo;
        if ((unsigned)r < RANGE) atomicAdd(&h[r], 1);  // LDS atomic
    }
    __syncthreads();
    unsigned short* c = cnt + s * CSTRIDE + lo;
    for (int i = tid; i < RANGE; i += 1024) c[i] = (unsigned short)h[i];
}

// ---------------- rowscan + partial-sum fusion ----------------
__global__ __launch_bounds__(256) void k_rowscan(unsigned short* __restrict__ cnt,
                                                 int* __restrict__ deg,
                                                 int* __restrict__ partial) {
    __shared__ int sred[256];
    int t = threadIdx.x;
    int r = blockIdx.x * 256 + t;
    int acc = 0;
    if (r < NN) {
#pragma unroll
        for (int s = 0; s < NSL; ++s) {
            int c = cnt[s * CSTRIDE + r];
            cnt[s * CSTRIDE + r] = (unsigned short)acc;  // exclusive within-row offset
            acc += c;
        }
        deg[r] = acc;
    }
    sred[t] = acc;
    __syncthreads();
    for (int off = 128; off > 0; off >>= 1) {
        if (t < off) sred[t] += sred[t + off];
        __syncthreads();
    }
    if (t == 0) partial[blockIdx.x] = sred[0];
}

// ---------------- scan of block partials ----------------
__global__ __launch_bounds__(256) void k_scan_top(int* __restrict__ partial) {
    __shared__ int s[256];
    int t = threadIdx.x;
    int v = (t < NPARTS) ? partial[t] : 0;
    s[t] = v;
    __syncthreads();
    for (int off = 1; off < 256; off <<= 1) {
        int x = (t >= off) ? s[t - off] : 0;
        __syncthreads();
        s[t] += x;
        __syncthreads();
    }
    if (t < NPARTS) partial[t] = s[t] - v;
}

__global__ __launch_bounds__(256) void k_scan_final(const int* __restrict__ deg,
                                                    const int* __restrict__ partial,
                                                    int* __restrict__ offs) {
    __shared__ int s[256];
    int t = threadIdx.x;
    int i = blockIdx.x * 256 + t;
    int v = (i < NN) ? deg[i] : 0;
    s[t] = v;
    __syncthreads();
    for (int off = 1; off < 256; off <<= 1) {
        int x = (t >= off) ? s[t - off] : 0;
        __syncthreads();
        s[t] += x;
        __syncthreads();
    }
    int excl = s[t] - v;
    if (i <= NN) offs[i] = partial[blockIdx.x] + excl;  // offs[NN] = NE
}

// ---------------- CSR fill via LDS cursor (NO global atomics) ----------------
__global__ __launch_bounds__(1024) void k_fillb(const int* __restrict__ row,
                                                const int* __restrict__ col,
                                                const int* __restrict__ offs,
                                                const unsigned short* __restrict__ cnt,
                                                int* __restrict__ csr) {
    __shared__ int cur[RANGE];
    int bid = blockIdx.x;
    int s   = bid >> 3;
    int rng = bid & 7;
    int lo = rng * RANGE;
    int tid = threadIdx.x;
    const unsigned short* c = cnt + s * CSTRIDE + lo;
    const int* o = offs + lo;
    for (int i = tid; i < RANGE; i += 1024) cur[i] = o[i] + c[i];
    __syncthreads();
    int beg = s * SLICEB;
    int end = beg + SLICEB;
    if (end > NE) end = NE;
    int e = beg + tid;
    for (; e + 3 * 1024 < end; e += 4 * 1024) {
        int r0 = __builtin_nontemporal_load(&row[e]) - lo;
        int r1 = __builtin_nontemporal_load(&row[e + 1024]) - lo;
        int r2 = __builtin_nontemporal_load(&row[e + 2048]) - lo;
        int r3 = __builtin_nontemporal_load(&row[e + 3072]) - lo;
        if ((unsigned)r0 < RANGE) {
            int pos = atomicAdd(&cur[r0], 1);
            csr[pos] = __builtin_nontemporal_load(&col[e]);
        }
        if ((unsigned)r1 < RANGE) {
            int pos = atomicAdd(&cur[r1], 1);
            csr[pos] = __builtin_nontemporal_load(&col[e + 1024]);
        }
        if ((unsigned)r2 < RANGE) {
            int pos = atomicAdd(&cur[r2], 1);
            csr[pos] = __builtin_nontemporal_load(&col[e + 2048]);
        }
        if ((unsigned)r3 < RANGE) {
            int pos = atomicAdd(&cur[r3], 1);
            csr[pos] = __builtin_nontemporal_load(&col[e + 3072]);
        }
    }
    for (; e < end; e += 1024) {
        int r = __builtin_nontemporal_load(&row[e]) - lo;
        if ((unsigned)r < RANGE) {
            int pos = atomicAdd(&cur[r], 1);
            csr[pos] = __builtin_nontemporal_load(&col[e]);
        }
    }
}

// ---------------- one propagation layer (fp8 gather, fp32 accum) ----------------
// 8 nodes per wave: lane>>3 = node in wave, lane&7 = feature-octet.
// Gather source is the fp8 mirror (3.2 MB -> L2-RESIDENT per XCD; 64 B/edge
// = half the bf16 bytes). Accumulation fp32. bf16 copies (xa16/xb16) are
// kept ONLY for the final out-assembly, so fp8 error never compounds there.
// PHASE 0: x0f8 -> v; store xa16(bf16) + xa8(fp8)
// PHASE 1: xa8  -> v; store xb16(bf16) + xb8(fp8)
// PHASE 2: xb8  -> v; out = 0.25*(emb + xa16 + xb16 + v)
template <int PHASE>
__global__ __launch_bounds__(256) void k_layer(const unsigned char* __restrict__ xin8,
                                               const float* __restrict__ emb,
                                               const unsigned short* __restrict__ xa16,
                                               const unsigned short* __restrict__ xb16,
                                               unsigned short* __restrict__ xout16,
                                               unsigned char* __restrict__ xout8,
                                               float* __restrict__ out,
                                               const int* __restrict__ offs,
                                               const int* __restrict__ csr) {
    int wid = (blockIdx.x * blockDim.x + threadIdx.x) >> 6;
    int lane = threadIdx.x & 63;
    int sub = lane >> 3;    // node within wave (0..7)
    int sl = lane & 7;      // feature-octet index (0..7)
    int n = 8 * wid + sub;
    if (n >= NN) return;
    int beg = offs[n];
    int end = offs[n + 1];
    const unsigned char* xq = xin8 + sl * 8;  // + c*64 bytes per neighbor, 8B-aligned

    float a0 = 0.f, a1 = 0.f, a2 = 0.f, a3 = 0.f, a4 = 0.f, a5 = 0.f, a6 = 0.f, a7 = 0.f;
    float b0 = 0.f, b1 = 0.f, b2 = 0.f, b3 = 0.f, b4 = 0.f, b5 = 0.f, b6 = 0.f, b7 = 0.f;
    int e = beg;
    for (; e + 8 <= end; e += 8) {
        int c0 = csr[e + 0], c1 = csr[e + 1], c2 = csr[e + 2], c3 = csr[e + 3];
        int c4 = csr[e + 4], c5 = csr[e + 5], c6 = csr[e + 6], c7 = csr[e + 7];
        uint2 u0 = *(const uint2*)(xq + c0 * 64);
        uint2 u1 = *(const uint2*)(xq + c1 * 64);
        uint2 u2 = *(const uint2*)(xq + c2 * 64);
        uint2 u3 = *(const uint2*)(xq + c3 * 64);
        uint2 u4 = *(const uint2*)(xq + c4 * 64);
        uint2 u5 = *(const uint2*)(xq + c5 * 64);
        uint2 u6 = *(const uint2*)(xq + c6 * 64);
        uint2 u7 = *(const uint2*)(xq + c7 * 64);
        f32x2 p;
        p = dec2<false>(u0.x); a0 += p[0]; a1 += p[1];
        p = dec2<true >(u0.x); a2 += p[0]; a3 += p[1];
        p = dec2<false>(u0.y); a4 += p[0]; a5 += p[1];
        p = dec2<true >(u0.y); a6 += p[0]; a7 += p[1];
        p = dec2<false>(u1.x); b0 += p[0]; b1 += p[1];
        p = dec2<true >(u1.x); b2 += p[0]; b3 += p[1];
        p = dec2<false>(u1.y); b4 += p[0]; b5 += p[1];
        p = dec2<true >(u1.y); b6 += p[0]; b7 += p[1];
        p = dec2<false>(u2.x); a0 += p[0]; a1 += p[1];
        p = dec2<true >(u2.x); a2 += p[0]; a3 += p[1];
        p = dec2<false>(u2.y); a4 += p[0]; a5 += p[1];
        p = dec2<true >(u2.y); a6 += p[0]; a7 += p[1];
        p = dec2<false>(u3.x); b0 += p[0]; b1 += p[1];
        p = dec2<true >(u3.x); b2 += p[0]; b3 += p[1];
        p = dec2<false>(u3.y); b4 += p[0]; b5 += p[1];
        p = dec2<true >(u3.y); b6 += p[0]; b7 += p[1];
        p = dec2<false>(u4.x); a0 += p[0]; a1 += p[1];
        p = dec2<true >(u4.x); a2 += p[0]; a3 += p[1];
        p = dec2<false>(u4.y); a4 += p[0]; a5 += p[1];
        p = dec2<true >(u4.y); a6 += p[0]; a7 += p[1];
        p = dec2<false>(u5.x); b0 += p[0]; b1 += p[1];
        p = dec2<true >(u5.x); b2 += p[0]; b3 += p[1];
        p = dec2<false>(u5.y); b4 += p[0]; b5 += p[1];
        p = dec2<true >(u5.y); b6 += p[0]; b7 += p[1];
        p = dec2<false>(u6.x); a0 += p[0]; a1 += p[1];
        p = dec2<true >(u6.x); a2 += p[0]; a3 += p[1];
        p = dec2<false>(u6.y); a4 += p[0]; a5 += p[1];
        p = dec2<true >(u6.y); a6 += p[0]; a7 += p[1];
        p = dec2<false>(u7.x); b0 += p[0]; b1 += p[1];
        p = dec2<true >(u7.x); b2 += p[0]; b3 += p[1];
        p = dec2<false>(u7.y); b4 += p[0]; b5 += p[1];
        p = dec2<true >(u7.y); b6 += p[0]; b7 += p[1];
    }
    for (; e < end; ++e) {
        uint2 u = *(const uint2*)(xq + csr[e] * 64);
        f32x2 p;
        p = dec2<false>(u.x); a0 += p[0]; a1 += p[1];
        p = dec2<true >(u.x); a2 += p[0]; a3 += p[1];
        p = dec2<false>(u.y); a4 += p[0]; a5 += p[1];
        p = dec2<true >(u.y); a6 += p[0]; a7 += p[1];
    }

    int d = end - beg;
    float inv = (d > 0) ? 1.0f / (float)d : 0.0f;
    float v0 = (a0 + b0) * inv;
    float v1 = (a1 + b1) * inv;
    float v2 = (a2 + b2) * inv;
    float v3 = (a3 + b3) * inv;
    float v4 = (a4 + b4) * inv;
    float v5 = (a5 + b5) * inv;
    float v6 = (a6 + b6) * inv;
    float v7 = (a7 + b7) * inv;

    int o = n * DIM + sl * 8;
    if (PHASE < 2) {
        uint4 pk16 = {(unsigned int)f2b(v0) | ((unsigned int)f2b(v1) << 16),
                      (unsigned int)f2b(v2) | ((unsigned int)f2b(v3) << 16),
                      (unsigned int)f2b(v4) | ((unsigned int)f2b(v5) << 16),
                      (unsigned int)f2b(v6) | ((unsigned int)f2b(v7) << 16)};
        *(uint4*)(xout16 + o) = pk16;
        uint2 pk8;
        pk8.x = enc4(v0, v1, v2, v3);
        pk8.y = enc4(v4, v5, v6, v7);
        *(uint2*)(xout8 + o) = pk8;
    } else {
        float4 e0 = *(const float4*)(emb + o);
        float4 e1 = *(const float4*)(emb + o + 4);
        uint4 ua = *(const uint4*)(xa16 + o);
        uint4 ub = *(const uint4*)(xb16 + o);
        float4 o0, o1;
        o0.x = 0.25f * (e0.x + blo(ua.x) + blo(ub.x) + v0);
        o0.y = 0.25f * (e0.y + bhi(ua.x) + bhi(ub.x) + v1);
        o0.z = 0.25f * (e0.z + blo(ua.y) + blo(ub.y) + v2);
        o0.w = 0.25f * (e0.w + bhi(ua.y) + bhi(ub.y) + v3);
        o1.x = 0.25f * (e1.x + blo(ua.z) + blo(ub.z) + v4);
        o1.y = 0.25f * (e1.y + bhi(ua.z) + bhi(ub.z) + v5);
        o1.z = 0.25f * (e1.z + blo(ua.w) + blo(ub.w) + v6);
        o1.w = 0.25f * (e1.w + bhi(ua.w) + bhi(ub.w) + v7);
        *(float4*)(out + o) = o0;
        *(float4*)(out + o + 4) = o1;
    }
}

extern "C" void kernel_launch(void* const* d_in, const int* in_sizes, int n_in,
                              void* d_out, int out_size, void* d_ws, size_t ws_size,
                              hipStream_t stream) {
    const int* edge = (const int*)d_in[0];
    const int* row = edge;        // edge_index[0]
    const int* col = edge + NE;   // edge_index[1]
    const float* emb = (const float*)d_in[1];
    float* out = (float*)d_out;

    // workspace layout (~34 MB)
    int* deg    = (int*)d_ws;                                // 50048 ints
    int* offs   = deg + 50048;                               // 50112 ints
    int* partial= offs + 50112;                              // 256 ints
    int* csr    = partial + 256;                             // 1250048 ints
    unsigned short* cnt = (unsigned short*)(csr + 1250048);  // 64*50048 ushort (6.4MB)
    unsigned short* xa16 = cnt + (size_t)NSL * CSTRIDE;      // 3.2M ushort
    unsigned short* xb16 = xa16 + NN * DIM;                  // 3.2M ushort
    unsigned char* x08 = (unsigned char*)(xb16 + NN * DIM);  // 3.2M bytes
    unsigned char* xa8 = x08 + NN * DIM;                     // 3.2M bytes
    unsigned char* xb8 = xa8 + NN * DIM;                     // 3.2M bytes

    k_cvt       <<<(NN * DIM / 8 + 255) / 256, 256, 0, stream>>>(emb, x08);
    k_hist      <<<NSL * 8, 1024, 0, stream>>>(row, cnt);
    k_rowscan   <<<NPARTS, 256, 0, stream>>>(cnt, deg, partial);
    k_scan_top  <<<1, 256, 0, stream>>>(partial);
    k_scan_final<<<NPARTS, 256, 0, stream>>>(deg, partial, offs);
    k_fillb     <<<NSL * 8, 1024, 0, stream>>>(row, col, offs, cnt, csr);

    // 8 nodes per wave: 6250 waves -> 1563 blocks of 256 (guard in-kernel)
    int layer_blocks = 1563;
    k_layer<0><<<layer_blocks, 256, 0, stream>>>(x08, nullptr, nullptr, nullptr, xa16, xa8, nullptr, offs, csr);
    k_layer<1><<<layer_blocks, 256, 0, stream>>>(xa8, nullptr, nullptr, nullptr, xb16, xb8, nullptr, offs, csr);
    k_layer<2><<<layer_blocks, 256, 0, stream>>>(xb8, emb, xa16, xb16, nullptr, nullptr, out, offs, csr);
}

// Round 21
// 102.034 us; speedup vs baseline: 1.6681x; 1.1508x over previous
//
#include <hip/hip_runtime.h>
#include <hip/hip_fp8.h>

#define NN 50000
#define DIM 64
#define NE 1250000
#define NPARTS 196  // ceil(50000/256)

// ---- counting-sort CSR build: 64 edge-slices x 8 row-ranges = 512 blocks
#define NSL 64
#define SLICEB 19532          // ceil(NE / NSL); 19532*64 = 1250048 >= NE
#define RANGE 6250            // NN / 8 rows per range
#define CSTRIDE 50048         // padded row stride of cnt matrix

typedef __attribute__((ext_vector_type(2))) float f32x2;

// bf16 helpers (RNE pack, cheap unpack)
__device__ __forceinline__ unsigned short f2b(float f) {
    unsigned int b = __builtin_bit_cast(unsigned int, f);
    b = (b + 0x7fffu + ((b >> 16) & 1u)) >> 16;
    return (unsigned short)b;
}
__device__ __forceinline__ float blo(unsigned int u) {
    return __builtin_bit_cast(float, u << 16);
}
__device__ __forceinline__ float bhi(unsigned int u) {
    return __builtin_bit_cast(float, u & 0xffff0000u);
}

// fp8 e4m3 (OCP) helpers — hardware cvt on gfx950; word-select must be constant.
template <bool HI>
__device__ __forceinline__ f32x2 dec2(unsigned int u) {
#if __has_builtin(__builtin_amdgcn_cvt_pk_f32_fp8)
    return __builtin_amdgcn_cvt_pk_f32_fp8(u, HI);
#else
    unsigned int b0 = HI ? ((u >> 16) & 0xff) : (u & 0xff);
    unsigned int b1 = HI ? ((u >> 24) & 0xff) : ((u >> 8) & 0xff);
    __hip_fp8_e4m3 t0, t1;
    t0.__x = (unsigned char)b0;
    t1.__x = (unsigned char)b1;
    f32x2 r;
    r[0] = (float)t0;
    r[1] = (float)t1;
    return r;
#endif
}
__device__ __forceinline__ unsigned int enc4(float v0, float v1, float v2, float v3) {
#if __has_builtin(__builtin_amdgcn_cvt_pk_fp8_f32)
    unsigned int r = 0;
    r = __builtin_amdgcn_cvt_pk_fp8_f32(v0, v1, r, false);
    r = __builtin_amdgcn_cvt_pk_fp8_f32(v2, v3, r, true);
    return r;
#else
    __hip_fp8_e4m3 t0(v0), t1(v1), t2(v2), t3(v3);
    return (unsigned int)t0.__x | ((unsigned int)t1.__x << 8) |
           ((unsigned int)t2.__x << 16) | ((unsigned int)t3.__x << 24);
#endif
}

// ---------------- fp32 emb -> fp8 gather mirror ----------------
__global__ __launch_bounds__(256) void k_cvt(const float* __restrict__ in,
                                             unsigned char* __restrict__ out8) {
    int t = blockIdx.x * blockDim.x + threadIdx.x;  // 8 elems per thread
    if (t >= NN * DIM / 8) return;
    const float4* p = (const float4*)in + t * 2;
    float4 a = p[0], b = p[1];
    uint2 pk;
    pk.x = enc4(a.x, a.y, a.z, a.w);
    pk.y = enc4(b.x, b.y, b.z, b.w);
    ((uint2*)out8)[t] = pk;
}

// ---------------- hist + bucket staging (NO global atomics) ----------------
// bid -> slice s = (bid&7)|((bid>>6)<<3), rng = (bid>>3)&7 (bid%8 == s%8:
// same-slice blocks co-scheduled on one XCD -> slice read into L2 once).
// In addition to the per-row histogram, stages each in-range edge as
// packed (r-lo)<<16 | col into the per-bucket region (s*8+rng)*SLICEB —
// so k_fillb never re-reads the 10 MB edge list (was 8x redundant, the
// r15-r17 latency/BW wall). Append via wave-aggregated ballot: one LDS
// atomic per wave, lanes write consecutive slots (coalesced).
__global__ __launch_bounds__(1024) void k_hist(const int* __restrict__ row,
                                               const int* __restrict__ col,
                                               unsigned short* __restrict__ cnt,
                                               unsigned int* __restrict__ stage,
                                               int* __restrict__ bsize) {
    __shared__ int h[RANGE];
    __shared__ int bcnt;
    int bid = blockIdx.x;
    int s   = (bid & 7) | ((bid >> 6) << 3);
    int rng = (bid >> 3) & 7;
    int lo = rng * RANGE;
    int tid = threadIdx.x;
    for (int i = tid; i < RANGE; i += 1024) h[i] = 0;
    if (tid == 0) bcnt = 0;
    __syncthreads();
    int beg = s * SLICEB;
    int end = beg + SLICEB;
    if (end > NE) end = NE;
    unsigned int* st = stage + (size_t)(s * 8 + rng) * SLICEB;
    int lane = tid & 63;
    for (int e = beg + tid; e < end; e += 1024) {
        int r = row[e] - lo;
        bool ok = (unsigned)r < RANGE;
        unsigned long long mask = __ballot(ok);
        if (ok) {
            int leader = __ffsll((long long)mask) - 1;
            int base = 0;
            if (lane == leader) base = atomicAdd(&bcnt, __popcll(mask));
            base = __shfl(base, leader);
            int off = __popcll(mask & ((1ull << lane) - 1ull));
            st[base + off] = ((unsigned int)r << 16) | (unsigned int)col[e];
            atomicAdd(&h[r], 1);  // LDS atomic
        }
    }
    __syncthreads();
    unsigned short* c = cnt + s * CSTRIDE + lo;
    for (int i = tid; i < RANGE; i += 1024) c[i] = (unsigned short)h[i];
    if (tid == 0) bsize[s * 8 + rng] = bcnt;
}

// ---------------- rowscan + partial-sum fusion ----------------
__global__ __launch_bounds__(256) void k_rowscan(unsigned short* __restrict__ cnt,
                                                 int* __restrict__ deg,
                                                 int* __restrict__ partial) {
    __shared__ int sred[256];
    int t = threadIdx.x;
    int r = blockIdx.x * 256 + t;
    int acc = 0;
    if (r < NN) {
#pragma unroll
        for (int s = 0; s < NSL; ++s) {
            int c = cnt[s * CSTRIDE + r];
            cnt[s * CSTRIDE + r] = (unsigned short)acc;  // exclusive within-row offset
            acc += c;
        }
        deg[r] = acc;
    }
    sred[t] = acc;
    __syncthreads();
    for (int off = 128; off > 0; off >>= 1) {
        if (t < off) sred[t] += sred[t + off];
        __syncthreads();
    }
    if (t == 0) partial[blockIdx.x] = sred[0];
}

// ---------------- scan of block partials ----------------
__global__ __launch_bounds__(256) void k_scan_top(int* __restrict__ partial) {
    __shared__ int s[256];
    int t = threadIdx.x;
    int v = (t < NPARTS) ? partial[t] : 0;
    s[t] = v;
    __syncthreads();
    for (int off = 1; off < 256; off <<= 1) {
        int x = (t >= off) ? s[t - off] : 0;
        __syncthreads();
        s[t] += x;
        __syncthreads();
    }
    if (t < NPARTS) partial[t] = s[t] - v;
}

__global__ __launch_bounds__(256) void k_scan_final(const int* __restrict__ deg,
                                                    const int* __restrict__ partial,
                                                    int* __restrict__ offs) {
    __shared__ int s[256];
    int t = threadIdx.x;
    int i = blockIdx.x * 256 + t;
    int v = (i < NN) ? deg[i] : 0;
    s[t] = v;
    __syncthreads();
    for (int off = 1; off < 256; off <<= 1) {
        int x = (t >= off) ? s[t - off] : 0;
        __syncthreads();
        s[t] += x;
        __syncthreads();
    }
    int excl = s[t] - v;
    if (i <= NN) offs[i] = partial[blockIdx.x] + excl;  // offs[NN] = NE
}

// ---------------- CSR fill from staged buckets (NO global atomics) ----------------
// bid -> s = bid>>3, rng = bid&7 (bid%8 == rng): all 64 blocks writing a
// range's csr region run on ONE XCD -> full-line evictions (WRITE ~5 MB).
// Reads ONLY its own staged bucket (~10 KB, L3-hot from k_hist) + the
// range's offs/cnt prologue — the 8x edge re-read is gone.
__global__ __launch_bounds__(1024) void k_fillb(const unsigned int* __restrict__ stage,
                                                const int* __restrict__ bsize,
                                                const int* __restrict__ offs,
                                                const unsigned short* __restrict__ cnt,
                                                int* __restrict__ csr) {
    __shared__ int cur[RANGE];
    int bid = blockIdx.x;
    int s   = bid >> 3;
    int rng = bid & 7;
    int lo = rng * RANGE;
    int tid = threadIdx.x;
    const unsigned short* c = cnt + s * CSTRIDE + lo;
    const int* o = offs + lo;
    for (int i = tid; i < RANGE; i += 1024) cur[i] = o[i] + c[i];
    __syncthreads();
    int nb = bsize[s * 8 + rng];
    const unsigned int* st = stage + (size_t)(s * 8 + rng) * SLICEB;
    for (int i = tid; i < nb; i += 1024) {
        unsigned int pk = st[i];
        int r = pk >> 16;
        int pos = atomicAdd(&cur[r], 1);  // LDS atomic
        csr[pos] = (int)(pk & 0xffffu);
    }
}

// ---------------- one propagation layer (fp8 gather, fp32 accum) ----------------
// 8 nodes per wave: lane>>3 = node in wave, lane&7 = feature-octet.
// Gather source: fp8 mirror (3.2 MB, per-XCD-L2-resident, 64 B/edge).
// bf16 copies kept ONLY for final out-assembly (fp8 error doesn't compound).
template <int PHASE>
__global__ __launch_bounds__(256) void k_layer(const unsigned char* __restrict__ xin8,
                                               const float* __restrict__ emb,
                                               const unsigned short* __restrict__ xa16,
                                               const unsigned short* __restrict__ xb16,
                                               unsigned short* __restrict__ xout16,
                                               unsigned char* __restrict__ xout8,
                                               float* __restrict__ out,
                                               const int* __restrict__ offs,
                                               const int* __restrict__ csr) {
    int wid = (blockIdx.x * blockDim.x + threadIdx.x) >> 6;
    int lane = threadIdx.x & 63;
    int sub = lane >> 3;    // node within wave (0..7)
    int sl = lane & 7;      // feature-octet index (0..7)
    int n = 8 * wid + sub;
    if (n >= NN) return;
    int beg = offs[n];
    int end = offs[n + 1];
    const unsigned char* xq = xin8 + sl * 8;  // + c*64 bytes per neighbor

    float a0 = 0.f, a1 = 0.f, a2 = 0.f, a3 = 0.f, a4 = 0.f, a5 = 0.f, a6 = 0.f, a7 = 0.f;
    float b0 = 0.f, b1 = 0.f, b2 = 0.f, b3 = 0.f, b4 = 0.f, b5 = 0.f, b6 = 0.f, b7 = 0.f;
    int e = beg;
    for (; e + 8 <= end; e += 8) {
        int c0 = csr[e + 0], c1 = csr[e + 1], c2 = csr[e + 2], c3 = csr[e + 3];
        int c4 = csr[e + 4], c5 = csr[e + 5], c6 = csr[e + 6], c7 = csr[e + 7];
        uint2 u0 = *(const uint2*)(xq + c0 * 64);
        uint2 u1 = *(const uint2*)(xq + c1 * 64);
        uint2 u2 = *(const uint2*)(xq + c2 * 64);
        uint2 u3 = *(const uint2*)(xq + c3 * 64);
        uint2 u4 = *(const uint2*)(xq + c4 * 64);
        uint2 u5 = *(const uint2*)(xq + c5 * 64);
        uint2 u6 = *(const uint2*)(xq + c6 * 64);
        uint2 u7 = *(const uint2*)(xq + c7 * 64);
        f32x2 p;
        p = dec2<false>(u0.x); a0 += p[0]; a1 += p[1];
        p = dec2<true >(u0.x); a2 += p[0]; a3 += p[1];
        p = dec2<false>(u0.y); a4 += p[0]; a5 += p[1];
        p = dec2<true >(u0.y); a6 += p[0]; a7 += p[1];
        p = dec2<false>(u1.x); b0 += p[0]; b1 += p[1];
        p = dec2<true >(u1.x); b2 += p[0]; b3 += p[1];
        p = dec2<false>(u1.y); b4 += p[0]; b5 += p[1];
        p = dec2<true >(u1.y); b6 += p[0]; b7 += p[1];
        p = dec2<false>(u2.x); a0 += p[0]; a1 += p[1];
        p = dec2<true >(u2.x); a2 += p[0]; a3 += p[1];
        p = dec2<false>(u2.y); a4 += p[0]; a5 += p[1];
        p = dec2<true >(u2.y); a6 += p[0]; a7 += p[1];
        p = dec2<false>(u3.x); b0 += p[0]; b1 += p[1];
        p = dec2<true >(u3.x); b2 += p[0]; b3 += p[1];
        p = dec2<false>(u3.y); b4 += p[0]; b5 += p[1];
        p = dec2<true >(u3.y); b6 += p[0]; b7 += p[1];
        p = dec2<false>(u4.x); a0 += p[0]; a1 += p[1];
        p = dec2<true >(u4.x); a2 += p[0]; a3 += p[1];
        p = dec2<false>(u4.y); a4 += p[0]; a5 += p[1];
        p = dec2<true >(u4.y); a6 += p[0]; a7 += p[1];
        p = dec2<false>(u5.x); b0 += p[0]; b1 += p[1];
        p = dec2<true >(u5.x); b2 += p[0]; b3 += p[1];
        p = dec2<false>(u5.y); b4 += p[0]; b5 += p[1];
        p = dec2<true >(u5.y); b6 += p[0]; b7 += p[1];
        p = dec2<false>(u6.x); a0 += p[0]; a1 += p[1];
        p = dec2<true >(u6.x); a2 += p[0]; a3 += p[1];
        p = dec2<false>(u6.y); a4 += p[0]; a5 += p[1];
        p = dec2<true >(u6.y); a6 += p[0]; a7 += p[1];
        p = dec2<false>(u7.x); b0 += p[0]; b1 += p[1];
        p = dec2<true >(u7.x); b2 += p[0]; b3 += p[1];
        p = dec2<false>(u7.y); b4 += p[0]; b5 += p[1];
        p = dec2<true >(u7.y); b6 += p[0]; b7 += p[1];
    }
    for (; e < end; ++e) {
        uint2 u = *(const uint2*)(xq + csr[e] * 64);
        f32x2 p;
        p = dec2<false>(u.x); a0 += p[0]; a1 += p[1];
        p = dec2<true >(u.x); a2 += p[0]; a3 += p[1];
        p = dec2<false>(u.y); a4 += p[0]; a5 += p[1];
        p = dec2<true >(u.y); a6 += p[0]; a7 += p[1];
    }

    int d = end - beg;
    float inv = (d > 0) ? 1.0f / (float)d : 0.0f;
    float v0 = (a0 + b0) * inv;
    float v1 = (a1 + b1) * inv;
    float v2 = (a2 + b2) * inv;
    float v3 = (a3 + b3) * inv;
    float v4 = (a4 + b4) * inv;
    float v5 = (a5 + b5) * inv;
    float v6 = (a6 + b6) * inv;
    float v7 = (a7 + b7) * inv;

    int o = n * DIM + sl * 8;
    if (PHASE < 2) {
        uint4 pk16 = {(unsigned int)f2b(v0) | ((unsigned int)f2b(v1) << 16),
                      (unsigned int)f2b(v2) | ((unsigned int)f2b(v3) << 16),
                      (unsigned int)f2b(v4) | ((unsigned int)f2b(v5) << 16),
                      (unsigned int)f2b(v6) | ((unsigned int)f2b(v7) << 16)};
        *(uint4*)(xout16 + o) = pk16;
        uint2 pk8;
        pk8.x = enc4(v0, v1, v2, v3);
        pk8.y = enc4(v4, v5, v6, v7);
        *(uint2*)(xout8 + o) = pk8;
    } else {
        float4 e0 = *(const float4*)(emb + o);
        float4 e1 = *(const float4*)(emb + o + 4);
        uint4 ua = *(const uint4*)(xa16 + o);
        uint4 ub = *(const uint4*)(xb16 + o);
        float4 o0, o1;
        o0.x = 0.25f * (e0.x + blo(ua.x) + blo(ub.x) + v0);
        o0.y = 0.25f * (e0.y + bhi(ua.x) + bhi(ub.x) + v1);
        o0.z = 0.25f * (e0.z + blo(ua.y) + blo(ub.y) + v2);
        o0.w = 0.25f * (e0.w + bhi(ua.y) + bhi(ub.y) + v3);
        o1.x = 0.25f * (e1.x + blo(ua.z) + blo(ub.z) + v4);
        o1.y = 0.25f * (e1.y + bhi(ua.z) + bhi(ub.z) + v5);
        o1.z = 0.25f * (e1.z + blo(ua.w) + blo(ub.w) + v6);
        o1.w = 0.25f * (e1.w + bhi(ua.w) + bhi(ub.w) + v7);
        *(float4*)(out + o) = o0;
        *(float4*)(out + o + 4) = o1;
    }
}

extern "C" void kernel_launch(void* const* d_in, const int* in_sizes, int n_in,
                              void* d_out, int out_size, void* d_ws, size_t ws_size,
                              hipStream_t stream) {
    const int* edge = (const int*)d_in[0];
    const int* row = edge;        // edge_index[0]
    const int* col = edge + NE;   // edge_index[1]
    const float* emb = (const float*)d_in[1];
    float* out = (float*)d_out;

    // workspace layout (~75 MB of 256 MB)
    int* deg    = (int*)d_ws;                                // 50048 ints
    int* offs   = deg + 50048;                               // 50112 ints
    int* partial= offs + 50112;                              // 256 ints
    int* bsize  = partial + 256;                             // 512 ints (pad 576)
    int* csr    = bsize + 576;                               // 1250048 ints
    unsigned short* cnt = (unsigned short*)(csr + 1250048);  // 64*50048 ushort (6.4MB)
    unsigned short* xa16 = cnt + (size_t)NSL * CSTRIDE;      // 3.2M ushort
    unsigned short* xb16 = xa16 + NN * DIM;                  // 3.2M ushort
    unsigned char* x08 = (unsigned char*)(xb16 + NN * DIM);  // 3.2M bytes
    unsigned char* xa8 = x08 + NN * DIM;                     // 3.2M bytes
    unsigned char* xb8 = xa8 + NN * DIM;                     // 3.2M bytes
    unsigned int* stage = (unsigned int*)(xb8 + NN * DIM);   // 512*19532 uints (40MB)

    k_cvt       <<<(NN * DIM / 8 + 255) / 256, 256, 0, stream>>>(emb, x08);
    k_hist      <<<NSL * 8, 1024, 0, stream>>>(row, col, cnt, stage, bsize);
    k_rowscan   <<<NPARTS, 256, 0, stream>>>(cnt, deg, partial);
    k_scan_top  <<<1, 256, 0, stream>>>(partial);
    k_scan_final<<<NPARTS, 256, 0, stream>>>(deg, partial, offs);
    k_fillb     <<<NSL * 8, 1024, 0, stream>>>(stage, bsize, offs, cnt, csr);

    // 8 nodes per wave: 6250 waves -> 1563 blocks of 256 (guard in-kernel)
    int layer_blocks = 1563;
    k_layer<0><<<layer_blocks, 256, 0, stream>>>(x08, nullptr, nullptr, nullptr, xa16, xa8, nullptr, offs, csr);
    k_layer<1><<<layer_blocks, 256, 0, stream>>>(xa8, nullptr, nullptr, nullptr, xb16, xb8, nullptr, offs, csr);
    k_layer<2><<<layer_blocks, 256, 0, stream>>>(xb8, emb, xa16, xb16, nullptr, nullptr, out, offs, csr);
}